// Round 5
// baseline (3435.086 us; speedup 1.0000x reference)
//
#include <hip/hip_runtime.h>
#include <hip/hip_bf16.h>
#include <math.h>

typedef unsigned short u16;
typedef unsigned int u32;

#define NB 8
#define SL 512
#define DM 256
#define DI 512
#define NTOK (NB*SL)           // 4096 tokens
#define EPSF 1e-5f

// ---------------- workspace (device globals; avoids ws_size dependence) ----
__device__ __align__(16) float g_feat[NTOK*DM];      // (B,L,256)
__device__ __align__(16) float g_xz  [NTOK*2*DI];    // (B,L,1024): 0..511 = x (later y), 512..1023 = z
__device__ __align__(16) float g_xc  [NTOK*DI];      // conv+silu output
__device__ __align__(16) float g_xdbl[NTOK*48];      // dt(16) | B(16) | C(16)
__device__ __align__(16) float g_dlt [NTOK*DI];      // delta
__device__ __align__(16) float g_outf[NTOK*DM];
__device__ __align__(16) float g_outb[NTOK*DM];

// ---------------- helpers ----------------
__device__ __forceinline__ float siluf(float v){ return v/(1.0f+__expf(-v)); }
__device__ __forceinline__ float softplusf(float v){ return fmaxf(v,0.0f)+log1pf(__expf(-fabsf(v))); }

// block-wide mean/var over 256 values (one per thread); red = shared float[8]
__device__ __forceinline__ void meanvar256(float v, float &mu, float &var, float* red){
  float s=v, q=v*v;
  #pragma unroll
  for (int off=32; off>0; off>>=1){ s+=__shfl_down(s,off); q+=__shfl_down(q,off); }
  int lane=threadIdx.x&63, w=threadIdx.x>>6;
  if (lane==0){ red[w]=s; red[4+w]=q; }
  __syncthreads();
  float st=red[0]+red[1]+red[2]+red[3];
  float qt=red[4]+red[5]+red[6]+red[7];
  mu=st*(1.0f/256.0f);
  var=qt*(1.0f/256.0f)-mu*mu;
}

// ---------------- tokenize + fusion matmul + LN ----------------
__global__ __launch_bounds__(256) void k_tokenize(
  const float* __restrict__ x, const float* __restrict__ embp, const float* __restrict__ embf,
  const float* __restrict__ embd, const float* __restrict__ Wlen, const float* __restrict__ blen,
  const float* __restrict__ Wiat, const float* __restrict__ biat, const float* __restrict__ Wfus,
  const float* __restrict__ bfus, const float* __restrict__ g, const float* __restrict__ bt,
  float* __restrict__ feat)
{
  int bl=blockIdx.x, t=threadIdx.x;
  __shared__ float cat[136];
  __shared__ float red[8];
  float xv0=x[bl*5+0], xv1=x[bl*5+1], xv2=x[bl*5+2], xv3=x[bl*5+3], xv4=x[bl*5+4];
  int proto=min(255,max(0,(int)xv0));
  int flags=min(63 ,max(0,(int)xv2));
  int dire =min(1  ,max(0,(int)xv4));
  if      (t<32 ) cat[t]=embp[proto*32+t];
  else if (t<64 ) cat[t]=fmaf(Wlen[t-32],xv1,blen[t-32]);
  else if (t<96 ) cat[t]=embf[flags*32+(t-64)];
  else if (t<128) cat[t]=fmaf(Wiat[t-96],xv3,biat[t-96]);
  else if (t<136) cat[t]=embd[dire*8+(t-128)];
  __syncthreads();
  float acc=bfus[t];
  #pragma unroll 8
  for (int k=0;k<136;k++) acc=fmaf(Wfus[t*136+k],cat[k],acc);
  float mu,var; meanvar256(acc,mu,var,red);
  feat[bl*256+t]=fmaf((acc-mu)*rsqrtf(var+EPSF),g[t],bt[t]);
}

// ---------------- generic GEMM: C[m,n] = sum_k A[m,k]*Bw[n,k]  (both fp32) ----
__global__ __launch_bounds__(256) void k_gemm(
  const float* __restrict__ A, int lda,
  const float* __restrict__ Bw, int K, int N,
  float* __restrict__ C, int ldc)
{
  __shared__ float As[16][64];
  __shared__ float Bs[16][64];
  int tid=threadIdx.x;
  int bm=blockIdx.y<<6, bn=blockIdx.x<<6;
  int lr=tid>>2;          // 0..63
  int lk=(tid&3)<<2;      // 0,4,8,12
  int tx=tid&15, ty=tid>>4;
  float acc[4][4]={};
  const float* Arow = A + (size_t)(bm+lr)*lda + lk;
  int brow = bn+lr;
  bool bv = brow < N;
  const float* Brow = Bw + (size_t)(bv? brow:0)*K + lk;
  for (int k0=0;k0<K;k0+=16){
    float4 av = *(const float4*)(Arow + k0);
    As[lk+0][lr]=av.x; As[lk+1][lr]=av.y; As[lk+2][lr]=av.z; As[lk+3][lr]=av.w;
    float4 bq=make_float4(0.f,0.f,0.f,0.f);
    if (bv) bq=*(const float4*)(Brow+k0);
    Bs[lk+0][lr]=bq.x; Bs[lk+1][lr]=bq.y; Bs[lk+2][lr]=bq.z; Bs[lk+3][lr]=bq.w;
    __syncthreads();
    #pragma unroll
    for (int k=0;k<16;k++){
      float a_[4], b_[4];
      #pragma unroll
      for (int i=0;i<4;i++) a_[i]=As[k][(ty<<2)+i];
      #pragma unroll
      for (int j=0;j<4;j++) b_[j]=Bs[k][(tx<<2)+j];
      #pragma unroll
      for (int i=0;i<4;i++){
        #pragma unroll
        for (int j=0;j<4;j++) acc[i][j]=fmaf(a_[i],b_[j],acc[i][j]);
      }
    }
    __syncthreads();
  }
  #pragma unroll
  for (int i=0;i<4;i++){
    int m=bm+(ty<<2)+i;
    #pragma unroll
    for (int j=0;j<4;j++){
      int n=bn+(tx<<2)+j;
      if (n<N) C[(size_t)m*ldc+n]=acc[i][j];
    }
  }
}

// ---------------- depthwise causal conv4 + SiLU (dir=1: anti-causal == flipped) ----
__global__ __launch_bounds__(256) void k_conv(const float* __restrict__ xz, const float* __restrict__ cw,
  const float* __restrict__ cb, float* __restrict__ xc, int dir)
{
  int idx=blockIdx.x*256+threadIdx.x;   // (b,l,d), d fastest
  int d=idx&511; int bl=idx>>9; int l=bl&511; int b=bl>>9;
  float acc=cb[d];
  #pragma unroll
  for (int k=0;k<4;k++){
    int lk = dir ? (l+3-k) : (l-3+k);
    if (lk>=0 && lk<512)
      acc=fmaf(cw[d*4+k], xz[(((size_t)(b*512+lk))<<10)+d], acc);
  }
  xc[idx]=siluf(acc);
}

// ---------------- delta = softplus(dt @ Wdt^T + bdt) ----------------
__global__ __launch_bounds__(256) void k_delta(const float* __restrict__ xdbl, const float* __restrict__ Wdt,
  const float* __restrict__ bdt, float* __restrict__ dlt)
{
  int blk=blockIdx.x; int bl=blk>>1; int d=((blk&1)<<8)+threadIdx.x;
  __shared__ float sdt[16];
  if (threadIdx.x<16) sdt[threadIdx.x]=xdbl[bl*48+threadIdx.x];
  __syncthreads();
  float acc=bdt[d];
  #pragma unroll
  for (int r=0;r<16;r++) acc=fmaf(sdt[r],Wdt[d*16+r],acc);
  dlt[bl*512+d]=softplusf(acc);
}

// ---------------- selective scan: one thread per (b,d), 16 states in regs --------
// writes y*silu(z) into xz cols 0..511 (x-half is dead by now)
__global__ __launch_bounds__(256) void k_scan(const float* __restrict__ dlt, const float* __restrict__ xc,
  const float* __restrict__ xdbl, const float* __restrict__ Alog, const float* __restrict__ Dp,
  float* __restrict__ xz, int dir)
{
  int b=blockIdx.x>>1;
  int d=((blockIdx.x&1)<<8)+threadIdx.x;
  float A[16], h[16];
  #pragma unroll
  for (int s=0;s<16;s++){ A[s]=-__expf(Alog[d*16+s]); h[s]=0.0f; }
  float Dv=Dp[d];
  for (int step=0;step<512;step++){
    int l = dir ? (511-step) : step;
    size_t bl=(size_t)b*512+l;
    float dl=dlt[bl*512+d];
    float xv=xc [bl*512+d];
    float du=dl*xv;
    const float* BC = xdbl + bl*48 + 16;   // block-uniform address -> scalar loads
    float y=0.0f;
    #pragma unroll
    for (int s=0;s<16;s++){
      float dA=__expf(dl*A[s]);
      h[s]=fmaf(dA,h[s],du*BC[s]);
      y=fmaf(h[s],BC[16+s],y);
    }
    y=fmaf(xv,Dv,y);
    float z=xz[(bl<<10)+512+d];
    xz[(bl<<10)+d]=y*siluf(z);
  }
}

// ---------------- residual + LayerNorm ----------------
__global__ __launch_bounds__(256) void k_resln(const float* __restrict__ of, const float* __restrict__ ob,
  float* __restrict__ feat, const float* __restrict__ g, const float* __restrict__ bb)
{
  int i=blockIdx.x*256+threadIdx.x;
  __shared__ float red[8];
  float v=of[i]+ob[i]+feat[i];
  float mu,var; meanvar256(v,mu,var,red);
  feat[i]=fmaf((v-mu)*rsqrtf(var+EPSF),g[threadIdx.x],bb[threadIdx.x]);
}

// ---------------- mean-pool + MLP head (fp32 output!) ----------------
__global__ __launch_bounds__(256) void k_head(const float* __restrict__ feat, const float* __restrict__ W1,
  const float* __restrict__ bb1, const float* __restrict__ W2, const float* __restrict__ bb2,
  float* __restrict__ out)
{
  int b=blockIdx.x, t=threadIdx.x;
  __shared__ float sp[256], sh[256];
  float acc=0.0f;
  for (int l=0;l<512;l++) acc+=feat[((size_t)b*512+l)*256+t];
  sp[t]=acc*(1.0f/512.0f);
  __syncthreads();
  float a=bb1[t];
  for (int k=0;k<256;k++) a=fmaf(sp[k],W1[t*256+k],a);
  sh[t]=fmaxf(a,0.0f);
  __syncthreads();
  float o=bb2[t];
  for (int k=0;k<256;k++) o=fmaf(sh[k],W2[t*256+k],o);
  out[b*256+t]=o;   // d_out is fp32 (reference output dtype = float32)
}

// ---------------- launch ----------------
extern "C" void kernel_launch(void* const* d_in, const int* in_sizes, int n_in,
                              void* d_out, int out_size, void* d_ws, size_t ws_size,
                              hipStream_t stream)
{
  (void)in_sizes; (void)n_in; (void)d_ws; (void)ws_size; (void)out_size;

  // Inputs: fp32 (proven R1/R2), dict order (proven R3/R4). Output: fp32.
  const float* X   =(const float*)d_in[0];
  const float* EMBP=(const float*)d_in[1];
  const float* EMBF=(const float*)d_in[2];
  const float* EMBD=(const float*)d_in[3];
  const float* WLEN=(const float*)d_in[4];
  const float* BLEN=(const float*)d_in[5];
  const float* WIAT=(const float*)d_in[6];
  const float* BIAT=(const float*)d_in[7];
  const float* WFUS=(const float*)d_in[8];
  const float* BFUS=(const float*)d_in[9];
  const float* GTOK=(const float*)d_in[10];
  const float* BTOK=(const float*)d_in[11];
  const float* GN  =(const float*)d_in[12];
  const float* BNb =(const float*)d_in[13];
  const float* WH1 =(const float*)d_in[14];
  const float* BH1 =(const float*)d_in[15];
  const float* WH2 =(const float*)d_in[16];
  const float* BH2 =(const float*)d_in[17];
  const float* INW[2]={(const float*)d_in[18],(const float*)d_in[27]};
  const float* CW [2]={(const float*)d_in[19],(const float*)d_in[28]};
  const float* CB [2]={(const float*)d_in[20],(const float*)d_in[29]};
  const float* XPW[2]={(const float*)d_in[21],(const float*)d_in[30]};
  const float* DTW[2]={(const float*)d_in[22],(const float*)d_in[31]};
  const float* DTB[2]={(const float*)d_in[23],(const float*)d_in[32]};
  const float* AL [2]={(const float*)d_in[24],(const float*)d_in[33]};
  const float* DP [2]={(const float*)d_in[25],(const float*)d_in[34]};
  const float* OW [2]={(const float*)d_in[26],(const float*)d_in[35]};

  float *feat,*xz,*xc,*xdbl,*dlt,*outf,*outb;
  hipGetSymbolAddress((void**)&feat, HIP_SYMBOL(g_feat));
  hipGetSymbolAddress((void**)&xz,   HIP_SYMBOL(g_xz));
  hipGetSymbolAddress((void**)&xc,   HIP_SYMBOL(g_xc));
  hipGetSymbolAddress((void**)&xdbl, HIP_SYMBOL(g_xdbl));
  hipGetSymbolAddress((void**)&dlt,  HIP_SYMBOL(g_dlt));
  hipGetSymbolAddress((void**)&outf, HIP_SYMBOL(g_outf));
  hipGetSymbolAddress((void**)&outb, HIP_SYMBOL(g_outb));

  k_tokenize<<<NTOK,256,0,stream>>>(X,EMBP,EMBF,EMBD,WLEN,BLEN,WIAT,BIAT,WFUS,BFUS,GTOK,BTOK,feat);
  for (int layer=0; layer<4; layer++){
    for (int dir=0; dir<2; dir++){
      // in_proj: (4096 x 1024) = feat (4096x256) @ Wp^T
      k_gemm<<<dim3(16,64),256,0,stream>>>(feat,256, INW[dir]+(size_t)layer*1024*256, 256,1024, xz,1024);
      // depthwise conv + silu
      k_conv<<<NTOK*DI/256,256,0,stream>>>(xz, CW[dir]+(size_t)layer*512*4, CB[dir]+(size_t)layer*512, xc, dir);
      // x_proj: (4096 x 48) = xc (4096x512) @ Wx^T
      k_gemm<<<dim3(1,64),256,0,stream>>>(xc,512, XPW[dir]+(size_t)layer*48*512, 512,48, xdbl,48);
      // delta
      k_delta<<<NTOK*2,256,0,stream>>>(xdbl, DTW[dir]+(size_t)layer*512*16, DTB[dir]+(size_t)layer*512, dlt);
      // selective scan (+ D skip + silu(z) gate), y -> xz cols 0..511
      k_scan<<<16,256,0,stream>>>(dlt,xc,xdbl, AL[dir]+(size_t)layer*512*16, DP[dir]+(size_t)layer*512, xz, dir);
      // out_proj: (4096 x 256) = y (lda 1024) @ Wo^T
      k_gemm<<<dim3(4,64),256,0,stream>>>(xz,1024, OW[dir]+(size_t)layer*256*512, 512,256, dir? outb:outf, 256);
    }
    k_resln<<<NTOK,256,0,stream>>>(outf,outb,feat,GN,BNb);
  }
  k_head<<<NB,256,0,stream>>>(feat,WH1,BH1,WH2,BH2,(float*)d_out);
}

// Round 6
// 2179.494 us; speedup vs baseline: 1.5761x; 1.5761x over previous
//
#include <hip/hip_runtime.h>
#include <hip/hip_bf16.h>
#include <math.h>

typedef unsigned short u16;
typedef unsigned int u32;

#define NB 8
#define SL 512
#define DM 256
#define DI 512
#define NTOK (NB*SL)           // 4096 tokens
#define EPSF 1e-5f

// per-direction buffer strides
#define XZS (NTOK*2*DI)        // xz: (B,L,1024)
#define XCS (NTOK*DI)          // xc / dlt: (B,L,512)
#define XDS (NTOK*48)          // xdbl: (B,L,48)

// ---------------- workspace (device globals) ----
__device__ __align__(16) float g_feat[NTOK*DM];
__device__ __align__(16) float g_xz  [2*XZS];    // [dir][B,L,1024]: 0..511 x->y, 512..1023 z
__device__ __align__(16) float g_xc  [2*XCS];    // conv+silu output
__device__ __align__(16) float g_xdbl[2*XDS];    // dt(16)|B(16)|C(16)
__device__ __align__(16) float g_dlt [2*XCS];    // delta
__device__ __align__(16) float g_outf[NTOK*DM];
__device__ __align__(16) float g_outb[NTOK*DM];

// ---------------- helpers ----------------
__device__ __forceinline__ float siluf(float v){ return v/(1.0f+__expf(-v)); }
__device__ __forceinline__ float softplusf(float v){ return fmaxf(v,0.0f)+log1pf(__expf(-fabsf(v))); }

__device__ __forceinline__ void meanvar256(float v, float &mu, float &var, float* red){
  float s=v, q=v*v;
  #pragma unroll
  for (int off=32; off>0; off>>=1){ s+=__shfl_down(s,off); q+=__shfl_down(q,off); }
  int lane=threadIdx.x&63, w=threadIdx.x>>6;
  if (lane==0){ red[w]=s; red[4+w]=q; }
  __syncthreads();
  float st=red[0]+red[1]+red[2]+red[3];
  float qt=red[4]+red[5]+red[6]+red[7];
  mu=st*(1.0f/256.0f);
  var=qt*(1.0f/256.0f)-mu*mu;
}

// ---------------- tokenize + fusion matmul + LN ----------------
__global__ __launch_bounds__(256) void k_tokenize(
  const float* __restrict__ x, const float* __restrict__ embp, const float* __restrict__ embf,
  const float* __restrict__ embd, const float* __restrict__ Wlen, const float* __restrict__ blen,
  const float* __restrict__ Wiat, const float* __restrict__ biat, const float* __restrict__ Wfus,
  const float* __restrict__ bfus, const float* __restrict__ g, const float* __restrict__ bt,
  float* __restrict__ feat)
{
  int bl=blockIdx.x, t=threadIdx.x;
  __shared__ float cat[136];
  __shared__ float red[8];
  float xv0=x[bl*5+0], xv1=x[bl*5+1], xv2=x[bl*5+2], xv3=x[bl*5+3], xv4=x[bl*5+4];
  int proto=min(255,max(0,(int)xv0));
  int flags=min(63 ,max(0,(int)xv2));
  int dire =min(1  ,max(0,(int)xv4));
  if      (t<32 ) cat[t]=embp[proto*32+t];
  else if (t<64 ) cat[t]=fmaf(Wlen[t-32],xv1,blen[t-32]);
  else if (t<96 ) cat[t]=embf[flags*32+(t-64)];
  else if (t<128) cat[t]=fmaf(Wiat[t-96],xv3,biat[t-96]);
  else if (t<136) cat[t]=embd[dire*8+(t-128)];
  __syncthreads();
  float acc=bfus[t];
  #pragma unroll 8
  for (int k=0;k<136;k++) acc=fmaf(Wfus[t*136+k],cat[k],acc);
  float mu,var; meanvar256(acc,mu,var,red);
  feat[bl*256+t]=fmaf((acc-mu)*rsqrtf(var+EPSF),g[t],bt[t]);
}

// ---------------- generic GEMM: C[m,n] = sum_k A[m,k]*Bw[n,k] ----------------
__global__ __launch_bounds__(256) void k_gemm(
  const float* __restrict__ A, int lda,
  const float* __restrict__ Bw, int K, int N,
  float* __restrict__ C, int ldc)
{
  __shared__ float As[16][64];
  __shared__ float Bs[16][64];
  int tid=threadIdx.x;
  int bm=blockIdx.y<<6, bn=blockIdx.x<<6;
  int lr=tid>>2;
  int lk=(tid&3)<<2;
  int tx=tid&15, ty=tid>>4;
  float acc[4][4]={};
  const float* Arow = A + (size_t)(bm+lr)*lda + lk;
  int brow = bn+lr;
  bool bv = brow < N;
  const float* Brow = Bw + (size_t)(bv? brow:0)*K + lk;
  for (int k0=0;k0<K;k0+=16){
    float4 av = *(const float4*)(Arow + k0);
    As[lk+0][lr]=av.x; As[lk+1][lr]=av.y; As[lk+2][lr]=av.z; As[lk+3][lr]=av.w;
    float4 bq=make_float4(0.f,0.f,0.f,0.f);
    if (bv) bq=*(const float4*)(Brow+k0);
    Bs[lk+0][lr]=bq.x; Bs[lk+1][lr]=bq.y; Bs[lk+2][lr]=bq.z; Bs[lk+3][lr]=bq.w;
    __syncthreads();
    #pragma unroll
    for (int k=0;k<16;k++){
      float a_[4], b_[4];
      #pragma unroll
      for (int i=0;i<4;i++) a_[i]=As[k][(ty<<2)+i];
      #pragma unroll
      for (int j=0;j<4;j++) b_[j]=Bs[k][(tx<<2)+j];
      #pragma unroll
      for (int i=0;i<4;i++){
        #pragma unroll
        for (int j=0;j<4;j++) acc[i][j]=fmaf(a_[i],b_[j],acc[i][j]);
      }
    }
    __syncthreads();
  }
  #pragma unroll
  for (int i=0;i<4;i++){
    int m=bm+(ty<<2)+i;
    #pragma unroll
    for (int j=0;j<4;j++){
      int n=bn+(tx<<2)+j;
      if (n<N) C[(size_t)m*ldc+n]=acc[i][j];
    }
  }
}

// ---------------- depthwise causal conv4 + SiLU ----------------
__global__ __launch_bounds__(256) void k_conv(const float* __restrict__ xz, const float* __restrict__ cw,
  const float* __restrict__ cb, float* __restrict__ xc, int dir)
{
  int idx=blockIdx.x*256+threadIdx.x;
  int d=idx&511; int bl=idx>>9; int l=bl&511; int b=bl>>9;
  float acc=cb[d];
  #pragma unroll
  for (int k=0;k<4;k++){
    int lk = dir ? (l+3-k) : (l-3+k);
    if (lk>=0 && lk<512)
      acc=fmaf(cw[d*4+k], xz[(((size_t)(b*512+lk))<<10)+d], acc);
  }
  xc[idx]=siluf(acc);
}

// ---------------- delta = softplus(dt @ Wdt^T + bdt) ----------------
__global__ __launch_bounds__(256) void k_delta(const float* __restrict__ xdbl, const float* __restrict__ Wdt,
  const float* __restrict__ bdt, float* __restrict__ dlt)
{
  int blk=blockIdx.x; int bl=blk>>1; int d=((blk&1)<<8)+threadIdx.x;
  __shared__ float sdt[16];
  if (threadIdx.x<16) sdt[threadIdx.x]=xdbl[bl*48+threadIdx.x];
  __syncthreads();
  float acc=bdt[d];
  #pragma unroll
  for (int r=0;r<16;r++) acc=fmaf(sdt[r],Wdt[d*16+r],acc);
  dlt[bl*512+d]=softplusf(acc);
}

// ---------------- selective scan, state-parallel -------------------------------
// one thread per (dir,b,d,s); s = tid&15 (16 states across lanes); both dirs in
// one dispatch. y = sum_s h*C via shfl_xor butterfly (width 16); lane s==0 adds
// x*D, gates with silu(z), stores into xz first half.
__global__ __launch_bounds__(256) void k_scan2(
  const float* __restrict__ dlt, const float* __restrict__ xc,
  const float* __restrict__ xdbl, float* __restrict__ xz,
  const float* __restrict__ ALf, const float* __restrict__ ALb,
  const float* __restrict__ DPf, const float* __restrict__ DPb)
{
  int dir = blockIdx.x >> 8;          // 512 blocks: 256 per direction
  int rem = blockIdx.x & 255;
  int b   = rem >> 5;                 // 8 batches
  int d   = ((rem & 31) << 4) + (threadIdx.x >> 4);  // 32 d-blocks x 16 d
  int s   = threadIdx.x & 15;

  const float* AL = dir ? ALb : ALf;
  const float* DP = dir ? DPb : DPf;
  const float* dl_p = dlt  + (size_t)dir*XCS;
  const float* xc_p = xc   + (size_t)dir*XCS;
  const float* xd_p = xdbl + (size_t)dir*XDS;
  float*       xz_p = xz   + (size_t)dir*XZS;

  float A  = -__expf(AL[d*16+s]);
  float Dv = DP[d];
  float h  = 0.0f;

  // prologue: load step 0
  int l = dir ? 511 : 0;
  size_t bl = (size_t)b*512 + l;
  float dl = dl_p[bl*512+d];
  float xv = xc_p[bl*512+d];
  float Bv = xd_p[bl*48+16+s];
  float Cv = xd_p[bl*48+32+s];
  float zv = xz_p[(bl<<10)+512+d];

  for (int step=0; step<512; step++){
    float dl_c=dl, xv_c=xv, Bv_c=Bv, Cv_c=Cv, zv_c=zv;
    size_t bl_c=bl;
    if (step<511){                      // prefetch next step
      int ln = dir ? (510-step) : (step+1);
      bl = (size_t)b*512 + ln;
      dl = dl_p[bl*512+d];
      xv = xc_p[bl*512+d];
      Bv = xd_p[bl*48+16+s];
      Cv = xd_p[bl*48+32+s];
      zv = xz_p[(bl<<10)+512+d];
    }
    float dA = __expf(dl_c*A);
    h = fmaf(dA, h, dl_c*xv_c*Bv_c);
    float y = h*Cv_c;
    y += __shfl_xor(y, 1, 16);
    y += __shfl_xor(y, 2, 16);
    y += __shfl_xor(y, 4, 16);
    y += __shfl_xor(y, 8, 16);
    if (s==0){
      y = fmaf(xv_c, Dv, y);
      xz_p[(bl_c<<10)+d] = y*siluf(zv_c);
    }
  }
}

// ---------------- residual + LayerNorm ----------------
__global__ __launch_bounds__(256) void k_resln(const float* __restrict__ of, const float* __restrict__ ob,
  float* __restrict__ feat, const float* __restrict__ g, const float* __restrict__ bb)
{
  int i=blockIdx.x*256+threadIdx.x;
  __shared__ float red[8];
  float v=of[i]+ob[i]+feat[i];
  float mu,var; meanvar256(v,mu,var,red);
  feat[i]=fmaf((v-mu)*rsqrtf(var+EPSF),g[threadIdx.x],bb[threadIdx.x]);
}

// ---------------- mean-pool + MLP head (fp32 output) ----------------
__global__ __launch_bounds__(256) void k_head(const float* __restrict__ feat, const float* __restrict__ W1,
  const float* __restrict__ bb1, const float* __restrict__ W2, const float* __restrict__ bb2,
  float* __restrict__ out)
{
  int b=blockIdx.x, t=threadIdx.x;
  __shared__ float sp[256], sh[256];
  float acc=0.0f;
  for (int l=0;l<512;l++) acc+=feat[((size_t)b*512+l)*256+t];
  sp[t]=acc*(1.0f/512.0f);
  __syncthreads();
  float a=bb1[t];
  for (int k=0;k<256;k++) a=fmaf(sp[k],W1[t*256+k],a);
  sh[t]=fmaxf(a,0.0f);
  __syncthreads();
  float o=bb2[t];
  for (int k=0;k<256;k++) o=fmaf(sh[k],W2[t*256+k],o);
  out[b*256+t]=o;
}

// ---------------- launch ----------------
extern "C" void kernel_launch(void* const* d_in, const int* in_sizes, int n_in,
                              void* d_out, int out_size, void* d_ws, size_t ws_size,
                              hipStream_t stream)
{
  (void)in_sizes; (void)n_in; (void)d_ws; (void)ws_size; (void)out_size;

  const float* X   =(const float*)d_in[0];
  const float* EMBP=(const float*)d_in[1];
  const float* EMBF=(const float*)d_in[2];
  const float* EMBD=(const float*)d_in[3];
  const float* WLEN=(const float*)d_in[4];
  const float* BLEN=(const float*)d_in[5];
  const float* WIAT=(const float*)d_in[6];
  const float* BIAT=(const float*)d_in[7];
  const float* WFUS=(const float*)d_in[8];
  const float* BFUS=(const float*)d_in[9];
  const float* GTOK=(const float*)d_in[10];
  const float* BTOK=(const float*)d_in[11];
  const float* GN  =(const float*)d_in[12];
  const float* BNb =(const float*)d_in[13];
  const float* WH1 =(const float*)d_in[14];
  const float* BH1 =(const float*)d_in[15];
  const float* WH2 =(const float*)d_in[16];
  const float* BH2 =(const float*)d_in[17];
  const float* INW[2]={(const float*)d_in[18],(const float*)d_in[27]};
  const float* CW [2]={(const float*)d_in[19],(const float*)d_in[28]};
  const float* CB [2]={(const float*)d_in[20],(const float*)d_in[29]};
  const float* XPW[2]={(const float*)d_in[21],(const float*)d_in[30]};
  const float* DTW[2]={(const float*)d_in[22],(const float*)d_in[31]};
  const float* DTB[2]={(const float*)d_in[23],(const float*)d_in[32]};
  const float* AL [2]={(const float*)d_in[24],(const float*)d_in[33]};
  const float* DP [2]={(const float*)d_in[25],(const float*)d_in[34]};
  const float* OW [2]={(const float*)d_in[26],(const float*)d_in[35]};

  float *feat,*xz,*xc,*xdbl,*dlt,*outf,*outb;
  hipGetSymbolAddress((void**)&feat, HIP_SYMBOL(g_feat));
  hipGetSymbolAddress((void**)&xz,   HIP_SYMBOL(g_xz));
  hipGetSymbolAddress((void**)&xc,   HIP_SYMBOL(g_xc));
  hipGetSymbolAddress((void**)&xdbl, HIP_SYMBOL(g_xdbl));
  hipGetSymbolAddress((void**)&dlt,  HIP_SYMBOL(g_dlt));
  hipGetSymbolAddress((void**)&outf, HIP_SYMBOL(g_outf));
  hipGetSymbolAddress((void**)&outb, HIP_SYMBOL(g_outb));

  k_tokenize<<<NTOK,256,0,stream>>>(X,EMBP,EMBF,EMBD,WLEN,BLEN,WIAT,BIAT,WFUS,BFUS,GTOK,BTOK,feat);
  for (int layer=0; layer<4; layer++){
    for (int dir=0; dir<2; dir++){
      float* xzd = xz + (size_t)dir*XZS;
      float* xcd = xc + (size_t)dir*XCS;
      float* xdd = xdbl + (size_t)dir*XDS;
      float* dld = dlt + (size_t)dir*XCS;
      k_gemm<<<dim3(16,64),256,0,stream>>>(feat,256, INW[dir]+(size_t)layer*1024*256, 256,1024, xzd,1024);
      k_conv<<<NTOK*DI/256,256,0,stream>>>(xzd, CW[dir]+(size_t)layer*512*4, CB[dir]+(size_t)layer*512, xcd, dir);
      k_gemm<<<dim3(1,64),256,0,stream>>>(xcd,512, XPW[dir]+(size_t)layer*48*512, 512,48, xdd,48);
      k_delta<<<NTOK*2,256,0,stream>>>(xdd, DTW[dir]+(size_t)layer*512*16, DTB[dir]+(size_t)layer*512, dld);
    }
    // both directions' scans in one dispatch (512 blocks)
    k_scan2<<<512,256,0,stream>>>(dlt,xc,xdbl,xz,
      AL[0]+(size_t)layer*512*16, AL[1]+(size_t)layer*512*16,
      DP[0]+(size_t)layer*512,    DP[1]+(size_t)layer*512);
    for (int dir=0; dir<2; dir++){
      float* xzd = xz + (size_t)dir*XZS;
      k_gemm<<<dim3(4,64),256,0,stream>>>(xzd,1024, OW[dir]+(size_t)layer*256*512, 512,256, dir? outb:outf, 256);
    }
    k_resln<<<NTOK,256,0,stream>>>(outf,outb,feat,GN,BNb);
  }
  k_head<<<NB,256,0,stream>>>(feat,WH1,BH1,WH2,BH2,(float*)d_out);
}

// Round 7
// 1560.476 us; speedup vs baseline: 2.2013x; 1.3967x over previous
//
#include <hip/hip_runtime.h>
#include <hip/hip_bf16.h>
#include <math.h>

typedef unsigned short u16;
typedef unsigned int u32;

#define NB 8
#define SL 512
#define DM 256
#define DI 512
#define NTOK (NB*SL)           // 4096 tokens
#define EPSF 1e-5f

// per-direction buffer strides
#define XZS (NTOK*2*DI)        // xz: (B,L,1024)
#define XCS (NTOK*DI)          // xc / dlt: (B,L,512)
#define XDS (NTOK*48)          // xdbl: (B,L,48)

// chunked scan
#define NC 16                  // chunks per sequence
#define CL 32                  // steps per chunk (NC*CL == SL)

// ---------------- workspace (device globals) ----
__device__ __align__(16) float g_feat[NTOK*DM];
__device__ __align__(16) float g_xz  [2*XZS];    // [dir][B,L,1024]: 0..511 x->y, 512..1023 z
__device__ __align__(16) float g_xc  [2*XCS];    // conv+silu output
__device__ __align__(16) float g_xdbl[2*XDS];    // dt(16)|B(16)|C(16)
__device__ __align__(16) float g_dlt [2*XCS];    // delta
__device__ __align__(16) float g_outf[NTOK*DM];
__device__ __align__(16) float g_outb[NTOK*DM];
__device__ __align__(16) float g_sumA[2*NB*NC*16*DI];  // chunk products  (8 MB)
__device__ __align__(16) float g_sumS[2*NB*NC*16*DI];  // chunk suffix sums (8 MB)

// ---------------- helpers ----------------
__device__ __forceinline__ float siluf(float v){ return v/(1.0f+__expf(-v)); }
__device__ __forceinline__ float softplusf(float v){ return fmaxf(v,0.0f)+log1pf(__expf(-fabsf(v))); }

__device__ __forceinline__ void meanvar256(float v, float &mu, float &var, float* red){
  float s=v, q=v*v;
  #pragma unroll
  for (int off=32; off>0; off>>=1){ s+=__shfl_down(s,off); q+=__shfl_down(q,off); }
  int lane=threadIdx.x&63, w=threadIdx.x>>6;
  if (lane==0){ red[w]=s; red[4+w]=q; }
  __syncthreads();
  float st=red[0]+red[1]+red[2]+red[3];
  float qt=red[4]+red[5]+red[6]+red[7];
  mu=st*(1.0f/256.0f);
  var=qt*(1.0f/256.0f)-mu*mu;
}

// ---------------- tokenize + fusion matmul + LN ----------------
__global__ __launch_bounds__(256) void k_tokenize(
  const float* __restrict__ x, const float* __restrict__ embp, const float* __restrict__ embf,
  const float* __restrict__ embd, const float* __restrict__ Wlen, const float* __restrict__ blen,
  const float* __restrict__ Wiat, const float* __restrict__ biat, const float* __restrict__ Wfus,
  const float* __restrict__ bfus, const float* __restrict__ g, const float* __restrict__ bt,
  float* __restrict__ feat)
{
  int bl=blockIdx.x, t=threadIdx.x;
  __shared__ float cat[136];
  __shared__ float red[8];
  float xv0=x[bl*5+0], xv1=x[bl*5+1], xv2=x[bl*5+2], xv3=x[bl*5+3], xv4=x[bl*5+4];
  int proto=min(255,max(0,(int)xv0));
  int flags=min(63 ,max(0,(int)xv2));
  int dire =min(1  ,max(0,(int)xv4));
  if      (t<32 ) cat[t]=embp[proto*32+t];
  else if (t<64 ) cat[t]=fmaf(Wlen[t-32],xv1,blen[t-32]);
  else if (t<96 ) cat[t]=embf[flags*32+(t-64)];
  else if (t<128) cat[t]=fmaf(Wiat[t-96],xv3,biat[t-96]);
  else if (t<136) cat[t]=embd[dire*8+(t-128)];
  __syncthreads();
  float acc=bfus[t];
  #pragma unroll 8
  for (int k=0;k<136;k++) acc=fmaf(Wfus[t*136+k],cat[k],acc);
  float mu,var; meanvar256(acc,mu,var,red);
  feat[bl*256+t]=fmaf((acc-mu)*rsqrtf(var+EPSF),g[t],bt[t]);
}

// ---------------- generic GEMM: C[m,n] = sum_k A[m,k]*Bw[n,k] ----------------
__global__ __launch_bounds__(256) void k_gemm(
  const float* __restrict__ A, int lda,
  const float* __restrict__ Bw, int K, int N,
  float* __restrict__ C, int ldc)
{
  __shared__ float As[16][64];
  __shared__ float Bs[16][64];
  int tid=threadIdx.x;
  int bm=blockIdx.y<<6, bn=blockIdx.x<<6;
  int lr=tid>>2;
  int lk=(tid&3)<<2;
  int tx=tid&15, ty=tid>>4;
  float acc[4][4]={};
  const float* Arow = A + (size_t)(bm+lr)*lda + lk;
  int brow = bn+lr;
  bool bv = brow < N;
  const float* Brow = Bw + (size_t)(bv? brow:0)*K + lk;
  for (int k0=0;k0<K;k0+=16){
    float4 av = *(const float4*)(Arow + k0);
    As[lk+0][lr]=av.x; As[lk+1][lr]=av.y; As[lk+2][lr]=av.z; As[lk+3][lr]=av.w;
    float4 bq=make_float4(0.f,0.f,0.f,0.f);
    if (bv) bq=*(const float4*)(Brow+k0);
    Bs[lk+0][lr]=bq.x; Bs[lk+1][lr]=bq.y; Bs[lk+2][lr]=bq.z; Bs[lk+3][lr]=bq.w;
    __syncthreads();
    #pragma unroll
    for (int k=0;k<16;k++){
      float a_[4], b_[4];
      #pragma unroll
      for (int i=0;i<4;i++) a_[i]=As[k][(ty<<2)+i];
      #pragma unroll
      for (int j=0;j<4;j++) b_[j]=Bs[k][(tx<<2)+j];
      #pragma unroll
      for (int i=0;i<4;i++){
        #pragma unroll
        for (int j=0;j<4;j++) acc[i][j]=fmaf(a_[i],b_[j],acc[i][j]);
      }
    }
    __syncthreads();
  }
  #pragma unroll
  for (int i=0;i<4;i++){
    int m=bm+(ty<<2)+i;
    #pragma unroll
    for (int j=0;j<4;j++){
      int n=bn+(tx<<2)+j;
      if (n<N) C[(size_t)m*ldc+n]=acc[i][j];
    }
  }
}

// ---------------- depthwise causal conv4 + SiLU ----------------
__global__ __launch_bounds__(256) void k_conv(const float* __restrict__ xz, const float* __restrict__ cw,
  const float* __restrict__ cb, float* __restrict__ xc, int dir)
{
  int idx=blockIdx.x*256+threadIdx.x;
  int d=idx&511; int bl=idx>>9; int l=bl&511; int b=bl>>9;
  float acc=cb[d];
  #pragma unroll
  for (int k=0;k<4;k++){
    int lk = dir ? (l+3-k) : (l-3+k);
    if (lk>=0 && lk<512)
      acc=fmaf(cw[d*4+k], xz[(((size_t)(b*512+lk))<<10)+d], acc);
  }
  xc[idx]=siluf(acc);
}

// ---------------- delta = softplus(dt @ Wdt^T + bdt) ----------------
__global__ __launch_bounds__(256) void k_delta(const float* __restrict__ xdbl, const float* __restrict__ Wdt,
  const float* __restrict__ bdt, float* __restrict__ dlt)
{
  int blk=blockIdx.x; int bl=blk>>1; int d=((blk&1)<<8)+threadIdx.x;
  __shared__ float sdt[16];
  if (threadIdx.x<16) sdt[threadIdx.x]=xdbl[bl*48+threadIdx.x];
  __syncthreads();
  float acc=bdt[d];
  #pragma unroll
  for (int r=0;r<16;r++) acc=fmaf(sdt[r],Wdt[d*16+r],acc);
  dlt[bl*512+d]=softplusf(acc);
}

// ---------------- chunked selective scan ---------------------------------------
// Pass A: per (dir,b,chunk,d) compute chunk summaries with h0=0:
//   ap[s] = prod_{l in chunk} a_l,  h[s] = local scan end state.
// Pass B: rebuild entry state from predecessor summaries, re-scan chunk,
//   y = sum_s h*C + x*D, gate silu(z), store into xz first half.
// lane = d (coalesced loads); B/C staged in LDS; states in registers.
__global__ __launch_bounds__(512) void k_scanA(
  const float* __restrict__ dlt, const float* __restrict__ xc,
  const float* __restrict__ xdbl,
  const float* __restrict__ ALf, const float* __restrict__ ALb,
  float* __restrict__ sumA, float* __restrict__ sumS)
{
  int c=blockIdx.x, b=blockIdx.y, dir=blockIdx.z;
  int d=threadIdx.x;
  const float* AL = dir?ALb:ALf;
  const float* dl_p = dlt + (size_t)dir*XCS;
  const float* xc_p = xc  + (size_t)dir*XCS;
  const float* xd_p = xdbl+ (size_t)dir*XDS;
  __shared__ float sBC[CL][32];   // [ll][0..15]=B, [16..31]=C
  for (int f=d; f<CL*32; f+=512){
    int ll=f>>5, j=f&31;
    int l = dir ? (511-(c*CL+ll)) : (c*CL+ll);
    sBC[ll][j] = xd_p[((size_t)b*512+l)*48+16+j];
  }
  __syncthreads();
  float A[16];
  const float4* ALv = (const float4*)(AL + d*16);
  #pragma unroll
  for (int i=0;i<4;i++){
    float4 v = ALv[i];
    A[4*i+0]=-__expf(v.x); A[4*i+1]=-__expf(v.y);
    A[4*i+2]=-__expf(v.z); A[4*i+3]=-__expf(v.w);
  }
  float h[16], ap[16];
  #pragma unroll
  for (int s=0;s<16;s++){ h[s]=0.f; ap[s]=1.f; }
  for (int ll=0; ll<CL; ll++){
    int l = dir ? (511-(c*CL+ll)) : (c*CL+ll);
    size_t bl=(size_t)b*512+l;
    float dl = dl_p[bl*512+d];
    float xv = xc_p[bl*512+d];
    float du = dl*xv;
    #pragma unroll
    for (int s=0;s<16;s++){
      float a = __expf(dl*A[s]);
      h[s]=fmaf(a,h[s],du*sBC[ll][s]);
      ap[s]*=a;
    }
  }
  size_t base = ((((size_t)dir*NB+b)*NC+c)*16)*DI + d;
  #pragma unroll
  for (int s=0;s<16;s++){
    sumA[base + (size_t)s*DI] = ap[s];
    sumS[base + (size_t)s*DI] = h[s];
  }
}

__global__ __launch_bounds__(512) void k_scanB(
  const float* __restrict__ dlt, const float* __restrict__ xc,
  const float* __restrict__ xdbl, float* __restrict__ xz,
  const float* __restrict__ ALf, const float* __restrict__ ALb,
  const float* __restrict__ DPf, const float* __restrict__ DPb,
  const float* __restrict__ sumA, const float* __restrict__ sumS)
{
  int c=blockIdx.x, b=blockIdx.y, dir=blockIdx.z;
  int d=threadIdx.x;
  const float* AL = dir?ALb:ALf;
  const float* DP = dir?DPb:DPf;
  const float* dl_p = dlt + (size_t)dir*XCS;
  const float* xc_p = xc  + (size_t)dir*XCS;
  const float* xd_p = xdbl+ (size_t)dir*XDS;
  float*       xz_p = xz  + (size_t)dir*XZS;
  __shared__ float sBC[CL][32];
  for (int f=d; f<CL*32; f+=512){
    int ll=f>>5, j=f&31;
    int l = dir ? (511-(c*CL+ll)) : (c*CL+ll);
    sBC[ll][j] = xd_p[((size_t)b*512+l)*48+16+j];
  }
  __syncthreads();
  float A[16];
  const float4* ALv = (const float4*)(AL + d*16);
  #pragma unroll
  for (int i=0;i<4;i++){
    float4 v = ALv[i];
    A[4*i+0]=-__expf(v.x); A[4*i+1]=-__expf(v.y);
    A[4*i+2]=-__expf(v.z); A[4*i+3]=-__expf(v.w);
  }
  // entry state = combine predecessor chunk summaries (in step order)
  float h[16];
  #pragma unroll
  for (int s=0;s<16;s++) h[s]=0.f;
  for (int cc=0; cc<c; cc++){
    size_t base = ((((size_t)dir*NB+b)*NC+cc)*16)*DI + d;
    #pragma unroll
    for (int s=0;s<16;s++){
      float a  = sumA[base + (size_t)s*DI];
      float sv = sumS[base + (size_t)s*DI];
      h[s]=fmaf(a,h[s],sv);
    }
  }
  float Dv = DP[d];
  for (int ll=0; ll<CL; ll++){
    int l = dir ? (511-(c*CL+ll)) : (c*CL+ll);
    size_t bl=(size_t)b*512+l;
    float dl = dl_p[bl*512+d];
    float xv = xc_p[bl*512+d];
    float zv = xz_p[(bl<<10)+512+d];
    float du = dl*xv;
    float y=0.f;
    #pragma unroll
    for (int s=0;s<16;s++){
      float a = __expf(dl*A[s]);
      h[s]=fmaf(a,h[s],du*sBC[ll][s]);
      y=fmaf(h[s],sBC[ll][16+s],y);
    }
    y=fmaf(xv,Dv,y);
    xz_p[(bl<<10)+d]=y*siluf(zv);
  }
}

// ---------------- residual + LayerNorm ----------------
__global__ __launch_bounds__(256) void k_resln(const float* __restrict__ of, const float* __restrict__ ob,
  float* __restrict__ feat, const float* __restrict__ g, const float* __restrict__ bb)
{
  int i=blockIdx.x*256+threadIdx.x;
  __shared__ float red[8];
  float v=of[i]+ob[i]+feat[i];
  float mu,var; meanvar256(v,mu,var,red);
  feat[i]=fmaf((v-mu)*rsqrtf(var+EPSF),g[threadIdx.x],bb[threadIdx.x]);
}

// ---------------- mean-pool + MLP head (fp32 output) ----------------
__global__ __launch_bounds__(256) void k_head(const float* __restrict__ feat, const float* __restrict__ W1,
  const float* __restrict__ bb1, const float* __restrict__ W2, const float* __restrict__ bb2,
  float* __restrict__ out)
{
  int b=blockIdx.x, t=threadIdx.x;
  __shared__ float sp[256], sh[256];
  float acc=0.0f;
  for (int l=0;l<512;l++) acc+=feat[((size_t)b*512+l)*256+t];
  sp[t]=acc*(1.0f/512.0f);
  __syncthreads();
  float a=bb1[t];
  for (int k=0;k<256;k++) a=fmaf(sp[k],W1[t*256+k],a);
  sh[t]=fmaxf(a,0.0f);
  __syncthreads();
  float o=bb2[t];
  for (int k=0;k<256;k++) o=fmaf(sh[k],W2[t*256+k],o);
  out[b*256+t]=o;
}

// ---------------- launch ----------------
extern "C" void kernel_launch(void* const* d_in, const int* in_sizes, int n_in,
                              void* d_out, int out_size, void* d_ws, size_t ws_size,
                              hipStream_t stream)
{
  (void)in_sizes; (void)n_in; (void)d_ws; (void)ws_size; (void)out_size;

  const float* X   =(const float*)d_in[0];
  const float* EMBP=(const float*)d_in[1];
  const float* EMBF=(const float*)d_in[2];
  const float* EMBD=(const float*)d_in[3];
  const float* WLEN=(const float*)d_in[4];
  const float* BLEN=(const float*)d_in[5];
  const float* WIAT=(const float*)d_in[6];
  const float* BIAT=(const float*)d_in[7];
  const float* WFUS=(const float*)d_in[8];
  const float* BFUS=(const float*)d_in[9];
  const float* GTOK=(const float*)d_in[10];
  const float* BTOK=(const float*)d_in[11];
  const float* GN  =(const float*)d_in[12];
  const float* BNb =(const float*)d_in[13];
  const float* WH1 =(const float*)d_in[14];
  const float* BH1 =(const float*)d_in[15];
  const float* WH2 =(const float*)d_in[16];
  const float* BH2 =(const float*)d_in[17];
  const float* INW[2]={(const float*)d_in[18],(const float*)d_in[27]};
  const float* CW [2]={(const float*)d_in[19],(const float*)d_in[28]};
  const float* CB [2]={(const float*)d_in[20],(const float*)d_in[29]};
  const float* XPW[2]={(const float*)d_in[21],(const float*)d_in[30]};
  const float* DTW[2]={(const float*)d_in[22],(const float*)d_in[31]};
  const float* DTB[2]={(const float*)d_in[23],(const float*)d_in[32]};
  const float* AL [2]={(const float*)d_in[24],(const float*)d_in[33]};
  const float* DP [2]={(const float*)d_in[25],(const float*)d_in[34]};
  const float* OW [2]={(const float*)d_in[26],(const float*)d_in[35]};

  float *feat,*xz,*xc,*xdbl,*dlt,*outf,*outb,*sumA,*sumS;
  hipGetSymbolAddress((void**)&feat, HIP_SYMBOL(g_feat));
  hipGetSymbolAddress((void**)&xz,   HIP_SYMBOL(g_xz));
  hipGetSymbolAddress((void**)&xc,   HIP_SYMBOL(g_xc));
  hipGetSymbolAddress((void**)&xdbl, HIP_SYMBOL(g_xdbl));
  hipGetSymbolAddress((void**)&dlt,  HIP_SYMBOL(g_dlt));
  hipGetSymbolAddress((void**)&outf, HIP_SYMBOL(g_outf));
  hipGetSymbolAddress((void**)&outb, HIP_SYMBOL(g_outb));
  hipGetSymbolAddress((void**)&sumA, HIP_SYMBOL(g_sumA));
  hipGetSymbolAddress((void**)&sumS, HIP_SYMBOL(g_sumS));

  k_tokenize<<<NTOK,256,0,stream>>>(X,EMBP,EMBF,EMBD,WLEN,BLEN,WIAT,BIAT,WFUS,BFUS,GTOK,BTOK,feat);
  for (int layer=0; layer<4; layer++){
    for (int dir=0; dir<2; dir++){
      float* xzd = xz + (size_t)dir*XZS;
      float* xcd = xc + (size_t)dir*XCS;
      float* xdd = xdbl + (size_t)dir*XDS;
      float* dld = dlt + (size_t)dir*XCS;
      k_gemm<<<dim3(16,64),256,0,stream>>>(feat,256, INW[dir]+(size_t)layer*1024*256, 256,1024, xzd,1024);
      k_conv<<<NTOK*DI/256,256,0,stream>>>(xzd, CW[dir]+(size_t)layer*512*4, CB[dir]+(size_t)layer*512, xcd, dir);
      k_gemm<<<dim3(1,64),256,0,stream>>>(xcd,512, XPW[dir]+(size_t)layer*48*512, 512,48, xdd,48);
      k_delta<<<NTOK*2,256,0,stream>>>(xdd, DTW[dir]+(size_t)layer*512*16, DTB[dir]+(size_t)layer*512, dld);
    }
    // chunked scan, both directions per launch
    k_scanA<<<dim3(NC,NB,2),512,0,stream>>>(dlt,xc,xdbl,
      AL[0]+(size_t)layer*512*16, AL[1]+(size_t)layer*512*16, sumA,sumS);
    k_scanB<<<dim3(NC,NB,2),512,0,stream>>>(dlt,xc,xdbl,xz,
      AL[0]+(size_t)layer*512*16, AL[1]+(size_t)layer*512*16,
      DP[0]+(size_t)layer*512,    DP[1]+(size_t)layer*512, sumA,sumS);
    for (int dir=0; dir<2; dir++){
      float* xzd = xz + (size_t)dir*XZS;
      k_gemm<<<dim3(4,64),256,0,stream>>>(xzd,1024, OW[dir]+(size_t)layer*256*512, 512,256, dir? outb:outf, 256);
    }
    k_resln<<<NTOK,256,0,stream>>>(outf,outb,feat,GN,BNb);
  }
  k_head<<<NB,256,0,stream>>>(feat,WH1,BH1,WH2,BH2,(float*)d_out);
}

// Round 8
// 1242.553 us; speedup vs baseline: 2.7645x; 1.2559x over previous
//
#include <hip/hip_runtime.h>
#include <hip/hip_bf16.h>
#include <math.h>

typedef unsigned short u16;
typedef unsigned int u32;

#define NB 8
#define SL 512
#define DM 256
#define DI 512
#define NTOK (NB*SL)           // 4096 tokens
#define EPSF 1e-5f

// per-direction buffer strides
#define XZS (NTOK*2*DI)        // xz: (B,L,1024)
#define XCS (NTOK*DI)          // xc / dlt: (B,L,512)
#define XDS (NTOK*48)          // xdbl: (B,L,48)

// chunked scan
#define NC 16
#define CL 32

// ---------------- workspace (device globals) ----
__device__ __align__(16) float g_feat[NTOK*DM];
__device__ __align__(16) float g_xz  [2*XZS];
__device__ __align__(16) float g_xc  [2*XCS];
__device__ __align__(16) float g_xdbl[2*XDS];
__device__ __align__(16) float g_dlt [2*XCS];
__device__ __align__(16) float g_outf[NTOK*DM];
__device__ __align__(16) float g_outb[NTOK*DM];
__device__ __align__(16) float g_sumA[2*NB*NC*16*DI];
__device__ __align__(16) float g_sumS[2*NB*NC*16*DI];

// ---------------- helpers ----------------
__device__ __forceinline__ float siluf(float v){ return v/(1.0f+__expf(-v)); }
__device__ __forceinline__ float softplusf(float v){ return fmaxf(v,0.0f)+log1pf(__expf(-fabsf(v))); }

// block-wide mean/var over 256 values; trailing sync so it can be called in a loop
__device__ __forceinline__ void meanvar256(float v, float &mu, float &var, float* red){
  float s=v, q=v*v;
  #pragma unroll
  for (int off=32; off>0; off>>=1){ s+=__shfl_down(s,off); q+=__shfl_down(q,off); }
  int lane=threadIdx.x&63, w=threadIdx.x>>6;
  if (lane==0){ red[w]=s; red[4+w]=q; }
  __syncthreads();
  float st=red[0]+red[1]+red[2]+red[3];
  float qt=red[4]+red[5]+red[6]+red[7];
  mu=st*(1.0f/256.0f);
  var=qt*(1.0f/256.0f)-mu*mu;
  __syncthreads();
}

// ---------------- tokenize: 16 tokens/block, LDS-staged Wfus ----------------
#define TT 16
__global__ __launch_bounds__(256) void k_tokenize(
  const float* __restrict__ x, const float* __restrict__ embp, const float* __restrict__ embf,
  const float* __restrict__ embd, const float* __restrict__ Wlen, const float* __restrict__ blen,
  const float* __restrict__ Wiat, const float* __restrict__ biat, const float* __restrict__ Wfus,
  const float* __restrict__ bfus, const float* __restrict__ g, const float* __restrict__ bt,
  float* __restrict__ feat)
{
  int bl0=blockIdx.x*TT, t=threadIdx.x;
  __shared__ float cat[TT][136];
  __shared__ float sW[256*9];       // 8 k-cols x 256 rows, stride 9 (bank-safe)
  __shared__ float red[8];
  // build cat for 16 tokens
  for (int f=t; f<TT*136; f+=256){
    int tok=f/136, j=f-tok*136, bl=bl0+tok;
    float cv;
    if      (j<32 ){ int p=min(255,max(0,(int)x[bl*5+0])); cv=embp[p*32+j]; }
    else if (j<64 ){ cv=fmaf(Wlen[j-32],x[bl*5+1],blen[j-32]); }
    else if (j<96 ){ int fl=min(63,max(0,(int)x[bl*5+2])); cv=embf[fl*32+(j-64)]; }
    else if (j<128){ cv=fmaf(Wiat[j-96],x[bl*5+3],biat[j-96]); }
    else           { int dd=min(1,max(0,(int)x[bl*5+4])); cv=embd[dd*8+(j-128)]; }
    cat[tok][j]=cv;
  }
  float acc[TT];
  float bf=bfus[t];
  #pragma unroll
  for (int tok=0;tok<TT;tok++) acc[tok]=bf;
  // 17 chunks of 8 k-columns
  for (int kk0=0; kk0<136; kk0+=8){
    __syncthreads();
    for (int f=t; f<2048; f+=256){
      int tr=f>>3, j=f&7;
      sW[tr*9+j]=Wfus[tr*136+kk0+j];
    }
    __syncthreads();
    #pragma unroll
    for (int j=0;j<8;j++){
      float w=sW[t*9+j];
      #pragma unroll
      for (int tok=0;tok<TT;tok++) acc[tok]=fmaf(w,cat[tok][kk0+j],acc[tok]);
    }
  }
  __syncthreads();
  float gv=g[t], bv=bt[t];
  for (int tok=0;tok<TT;tok++){
    float mu,var; meanvar256(acc[tok],mu,var,red);
    feat[(size_t)(bl0+tok)*256+t]=fmaf((acc[tok]-mu)*rsqrtf(var+EPSF),gv,bv);
  }
}

// ---------------- templated fp32 GEMM: C[m,n] = sum_k A[m,k]*Bw[n,k] ------------
// blockIdx.z selects (A,B,C) set -> both directions in one dispatch.
// LDS rows padded +4 floats (rows stay 16B-aligned; scatter writes 2-way = free).
template<int BM,int BN,int TM,int TN>
__global__ __launch_bounds__(256) void k_gemmT(
  const float* __restrict__ A0, const float* __restrict__ A1, int lda,
  const float* __restrict__ B0, const float* __restrict__ B1, int K, int N,
  float* __restrict__ C0, float* __restrict__ C1, int ldc)
{
  const float* A = blockIdx.z ? A1 : A0;
  const float* Bw= blockIdx.z ? B1 : B0;
  float*       C = blockIdx.z ? C1 : C0;
  __shared__ float As[16][BM+4];
  __shared__ float Bs[16][BN+4];
  int tid=threadIdx.x;
  int bm=blockIdx.y*BM, bn=blockIdx.x*BN;
  constexpr int NTX = BN/TN;
  int tx = tid % NTX, ty = tid / NTX;
  int tm0 = ty*TM, tn0 = tx*TN;
  float acc[TM][TN]={};
  for (int k0=0;k0<K;k0+=16){
    #pragma unroll
    for (int i=0;i<BM/64;i++){
      int u = tid + i*256;
      int kq=(u&3)<<2, m=u>>2;
      float4 v = *(const float4*)(A + (size_t)(bm+m)*lda + k0 + kq);
      As[kq+0][m]=v.x; As[kq+1][m]=v.y; As[kq+2][m]=v.z; As[kq+3][m]=v.w;
    }
    #pragma unroll
    for (int i=0;i<BN/64;i++){
      int u = tid + i*256;
      int kq=(u&3)<<2, n=u>>2;
      float4 v = make_float4(0.f,0.f,0.f,0.f);
      if (bn+n < N) v = *(const float4*)(Bw + (size_t)(bn+n)*K + k0 + kq);
      Bs[kq+0][n]=v.x; Bs[kq+1][n]=v.y; Bs[kq+2][n]=v.z; Bs[kq+3][n]=v.w;
    }
    __syncthreads();
    #pragma unroll
    for (int k=0;k<16;k++){
      float a[TM], b[TN];
      #pragma unroll
      for (int i=0;i<TM;i+=4) *(float4*)&a[i] = *(const float4*)&As[k][tm0+i];
      #pragma unroll
      for (int j=0;j<TN;j+=4) *(float4*)&b[j] = *(const float4*)&Bs[k][tn0+j];
      #pragma unroll
      for (int i=0;i<TM;i++)
        #pragma unroll
        for (int j=0;j<TN;j++) acc[i][j]=fmaf(a[i],b[j],acc[i][j]);
    }
    __syncthreads();
  }
  #pragma unroll
  for (int i=0;i<TM;i++){
    int m=bm+tm0+i;
    #pragma unroll
    for (int j=0;j<TN;j+=4){
      int n=bn+tn0+j;
      if (n < N) *(float4*)(C + (size_t)m*ldc + n) = *(float4*)&acc[i][j];
    }
  }
}

// ---------------- depthwise causal conv4 + SiLU, both dirs ----------------
__global__ __launch_bounds__(256) void k_conv2(const float* __restrict__ xz,
  const float* __restrict__ cw0, const float* __restrict__ cw1,
  const float* __restrict__ cb0, const float* __restrict__ cb1,
  float* __restrict__ xc)
{
  int dir=blockIdx.y;
  const float* xzp = xz + (size_t)dir*XZS;
  float*       xcp = (float*)xc + (size_t)dir*XCS;
  const float* cw = dir?cw1:cw0;
  const float* cb = dir?cb1:cb0;
  int idx=blockIdx.x*256+threadIdx.x;
  int d=idx&511; int bl=idx>>9; int l=bl&511; int b=bl>>9;
  float acc=cb[d];
  #pragma unroll
  for (int k=0;k<4;k++){
    int lk = dir ? (l+3-k) : (l-3+k);
    if (lk>=0 && lk<512)
      acc=fmaf(cw[d*4+k], xzp[(((size_t)(b*512+lk))<<10)+d], acc);
  }
  xcp[idx]=siluf(acc);
}

// ---------------- delta = softplus(dt @ Wdt^T + bdt), both dirs ----------------
__global__ __launch_bounds__(256) void k_delta2(const float* __restrict__ xdbl,
  const float* __restrict__ W0, const float* __restrict__ W1,
  const float* __restrict__ b0, const float* __restrict__ b1,
  float* __restrict__ dlt)
{
  int dir=blockIdx.y;
  const float* xd = xdbl + (size_t)dir*XDS;
  float*       dl = dlt  + (size_t)dir*XCS;
  const float* Wdt = dir?W1:W0;
  const float* bdt = dir?b1:b0;
  int blk=blockIdx.x; int bl=blk>>1; int d=((blk&1)<<8)+threadIdx.x;
  __shared__ float sdt[16];
  if (threadIdx.x<16) sdt[threadIdx.x]=xd[bl*48+threadIdx.x];
  __syncthreads();
  float acc=bdt[d];
  #pragma unroll
  for (int r=0;r<16;r++) acc=fmaf(sdt[r],Wdt[d*16+r],acc);
  dl[bl*512+d]=softplusf(acc);
}

// ---------------- chunked selective scan (unchanged from R7) -------------------
__global__ __launch_bounds__(512) void k_scanA(
  const float* __restrict__ dlt, const float* __restrict__ xc,
  const float* __restrict__ xdbl,
  const float* __restrict__ ALf, const float* __restrict__ ALb,
  float* __restrict__ sumA, float* __restrict__ sumS)
{
  int c=blockIdx.x, b=blockIdx.y, dir=blockIdx.z;
  int d=threadIdx.x;
  const float* AL = dir?ALb:ALf;
  const float* dl_p = dlt + (size_t)dir*XCS;
  const float* xc_p = xc  + (size_t)dir*XCS;
  const float* xd_p = xdbl+ (size_t)dir*XDS;
  __shared__ float sBC[CL][32];
  for (int f=d; f<CL*32; f+=512){
    int ll=f>>5, j=f&31;
    int l = dir ? (511-(c*CL+ll)) : (c*CL+ll);
    sBC[ll][j] = xd_p[((size_t)b*512+l)*48+16+j];
  }
  __syncthreads();
  float A[16];
  const float4* ALv = (const float4*)(AL + d*16);
  #pragma unroll
  for (int i=0;i<4;i++){
    float4 v = ALv[i];
    A[4*i+0]=-__expf(v.x); A[4*i+1]=-__expf(v.y);
    A[4*i+2]=-__expf(v.z); A[4*i+3]=-__expf(v.w);
  }
  float h[16], ap[16];
  #pragma unroll
  for (int s=0;s<16;s++){ h[s]=0.f; ap[s]=1.f; }
  for (int ll=0; ll<CL; ll++){
    int l = dir ? (511-(c*CL+ll)) : (c*CL+ll);
    size_t bl=(size_t)b*512+l;
    float dl = dl_p[bl*512+d];
    float xv = xc_p[bl*512+d];
    float du = dl*xv;
    #pragma unroll
    for (int s=0;s<16;s++){
      float a = __expf(dl*A[s]);
      h[s]=fmaf(a,h[s],du*sBC[ll][s]);
      ap[s]*=a;
    }
  }
  size_t base = ((((size_t)dir*NB+b)*NC+c)*16)*DI + d;
  #pragma unroll
  for (int s=0;s<16;s++){
    sumA[base + (size_t)s*DI] = ap[s];
    sumS[base + (size_t)s*DI] = h[s];
  }
}

__global__ __launch_bounds__(512) void k_scanB(
  const float* __restrict__ dlt, const float* __restrict__ xc,
  const float* __restrict__ xdbl, float* __restrict__ xz,
  const float* __restrict__ ALf, const float* __restrict__ ALb,
  const float* __restrict__ DPf, const float* __restrict__ DPb,
  const float* __restrict__ sumA, const float* __restrict__ sumS)
{
  int c=blockIdx.x, b=blockIdx.y, dir=blockIdx.z;
  int d=threadIdx.x;
  const float* AL = dir?ALb:ALf;
  const float* DP = dir?DPb:DPf;
  const float* dl_p = dlt + (size_t)dir*XCS;
  const float* xc_p = xc  + (size_t)dir*XCS;
  const float* xd_p = xdbl+ (size_t)dir*XDS;
  float*       xz_p = xz  + (size_t)dir*XZS;
  __shared__ float sBC[CL][32];
  for (int f=d; f<CL*32; f+=512){
    int ll=f>>5, j=f&31;
    int l = dir ? (511-(c*CL+ll)) : (c*CL+ll);
    sBC[ll][j] = xd_p[((size_t)b*512+l)*48+16+j];
  }
  __syncthreads();
  float A[16];
  const float4* ALv = (const float4*)(AL + d*16);
  #pragma unroll
  for (int i=0;i<4;i++){
    float4 v = ALv[i];
    A[4*i+0]=-__expf(v.x); A[4*i+1]=-__expf(v.y);
    A[4*i+2]=-__expf(v.z); A[4*i+3]=-__expf(v.w);
  }
  float h[16];
  #pragma unroll
  for (int s=0;s<16;s++) h[s]=0.f;
  for (int cc=0; cc<c; cc++){
    size_t base = ((((size_t)dir*NB+b)*NC+cc)*16)*DI + d;
    #pragma unroll
    for (int s=0;s<16;s++){
      float a  = sumA[base + (size_t)s*DI];
      float sv = sumS[base + (size_t)s*DI];
      h[s]=fmaf(a,h[s],sv);
    }
  }
  float Dv = DP[d];
  for (int ll=0; ll<CL; ll++){
    int l = dir ? (511-(c*CL+ll)) : (c*CL+ll);
    size_t bl=(size_t)b*512+l;
    float dl = dl_p[bl*512+d];
    float xv = xc_p[bl*512+d];
    float zv = xz_p[(bl<<10)+512+d];
    float du = dl*xv;
    float y=0.f;
    #pragma unroll
    for (int s=0;s<16;s++){
      float a = __expf(dl*A[s]);
      h[s]=fmaf(a,h[s],du*sBC[ll][s]);
      y=fmaf(h[s],sBC[ll][16+s],y);
    }
    y=fmaf(xv,Dv,y);
    xz_p[(bl<<10)+d]=y*siluf(zv);
  }
}

// ---------------- residual + LayerNorm ----------------
__global__ __launch_bounds__(256) void k_resln(const float* __restrict__ of, const float* __restrict__ ob,
  float* __restrict__ feat, const float* __restrict__ g, const float* __restrict__ bb)
{
  int i=blockIdx.x*256+threadIdx.x;
  __shared__ float red[8];
  float v=of[i]+ob[i]+feat[i];
  float mu,var; meanvar256(v,mu,var,red);
  feat[i]=fmaf((v-mu)*rsqrtf(var+EPSF),g[threadIdx.x],bb[threadIdx.x]);
}

// ---------------- mean-pool + MLP head (fp32 output) ----------------
__global__ __launch_bounds__(256) void k_head(const float* __restrict__ feat, const float* __restrict__ W1,
  const float* __restrict__ bb1, const float* __restrict__ W2, const float* __restrict__ bb2,
  float* __restrict__ out)
{
  int b=blockIdx.x, t=threadIdx.x;
  __shared__ float sp[256], sh[256];
  float acc=0.0f;
  for (int l=0;l<512;l++) acc+=feat[((size_t)b*512+l)*256+t];
  sp[t]=acc*(1.0f/512.0f);
  __syncthreads();
  float a=bb1[t];
  for (int k=0;k<256;k++) a=fmaf(sp[k],W1[t*256+k],a);
  sh[t]=fmaxf(a,0.0f);
  __syncthreads();
  float o=bb2[t];
  for (int k=0;k<256;k++) o=fmaf(sh[k],W2[t*256+k],o);
  out[b*256+t]=o;
}

// ---------------- launch ----------------
extern "C" void kernel_launch(void* const* d_in, const int* in_sizes, int n_in,
                              void* d_out, int out_size, void* d_ws, size_t ws_size,
                              hipStream_t stream)
{
  (void)in_sizes; (void)n_in; (void)d_ws; (void)ws_size; (void)out_size;

  const float* X   =(const float*)d_in[0];
  const float* EMBP=(const float*)d_in[1];
  const float* EMBF=(const float*)d_in[2];
  const float* EMBD=(const float*)d_in[3];
  const float* WLEN=(const float*)d_in[4];
  const float* BLEN=(const float*)d_in[5];
  const float* WIAT=(const float*)d_in[6];
  const float* BIAT=(const float*)d_in[7];
  const float* WFUS=(const float*)d_in[8];
  const float* BFUS=(const float*)d_in[9];
  const float* GTOK=(const float*)d_in[10];
  const float* BTOK=(const float*)d_in[11];
  const float* GN  =(const float*)d_in[12];
  const float* BNb =(const float*)d_in[13];
  const float* WH1 =(const float*)d_in[14];
  const float* BH1 =(const float*)d_in[15];
  const float* WH2 =(const float*)d_in[16];
  const float* BH2 =(const float*)d_in[17];
  const float* INW[2]={(const float*)d_in[18],(const float*)d_in[27]};
  const float* CW [2]={(const float*)d_in[19],(const float*)d_in[28]};
  const float* CB [2]={(const float*)d_in[20],(const float*)d_in[29]};
  const float* XPW[2]={(const float*)d_in[21],(const float*)d_in[30]};
  const float* DTW[2]={(const float*)d_in[22],(const float*)d_in[31]};
  const float* DTB[2]={(const float*)d_in[23],(const float*)d_in[32]};
  const float* AL [2]={(const float*)d_in[24],(const float*)d_in[33]};
  const float* DP [2]={(const float*)d_in[25],(const float*)d_in[34]};
  const float* OW [2]={(const float*)d_in[26],(const float*)d_in[35]};

  float *feat,*xz,*xc,*xdbl,*dlt,*outf,*outb,*sumA,*sumS;
  hipGetSymbolAddress((void**)&feat, HIP_SYMBOL(g_feat));
  hipGetSymbolAddress((void**)&xz,   HIP_SYMBOL(g_xz));
  hipGetSymbolAddress((void**)&xc,   HIP_SYMBOL(g_xc));
  hipGetSymbolAddress((void**)&xdbl, HIP_SYMBOL(g_xdbl));
  hipGetSymbolAddress((void**)&dlt,  HIP_SYMBOL(g_dlt));
  hipGetSymbolAddress((void**)&outf, HIP_SYMBOL(g_outf));
  hipGetSymbolAddress((void**)&outb, HIP_SYMBOL(g_outb));
  hipGetSymbolAddress((void**)&sumA, HIP_SYMBOL(g_sumA));
  hipGetSymbolAddress((void**)&sumS, HIP_SYMBOL(g_sumS));

  k_tokenize<<<NTOK/TT,256,0,stream>>>(X,EMBP,EMBF,EMBD,WLEN,BLEN,WIAT,BIAT,WFUS,BFUS,GTOK,BTOK,feat);
  for (int layer=0; layer<4; layer++){
    // in_proj, both dirs: (4096x1024) = feat(4096x256) @ Wp^T
    k_gemmT<128,128,8,8><<<dim3(8,32,2),256,0,stream>>>(
      feat,feat,256,
      INW[0]+(size_t)layer*1024*256, INW[1]+(size_t)layer*1024*256, 256,1024,
      xz, xz+XZS, 1024);
    // conv + silu, both dirs
    k_conv2<<<dim3(NTOK*DI/256,2),256,0,stream>>>(xz,
      CW[0]+(size_t)layer*512*4, CW[1]+(size_t)layer*512*4,
      CB[0]+(size_t)layer*512,   CB[1]+(size_t)layer*512, xc);
    // x_proj, both dirs: (4096x48) = xc(4096x512) @ Wx^T
    k_gemmT<64,64,4,4><<<dim3(1,64,2),256,0,stream>>>(
      xc, xc+XCS, 512,
      XPW[0]+(size_t)layer*48*512, XPW[1]+(size_t)layer*48*512, 512,48,
      xdbl, xdbl+XDS, 48);
    // delta, both dirs
    k_delta2<<<dim3(NTOK*2,2),256,0,stream>>>(xdbl,
      DTW[0]+(size_t)layer*512*16, DTW[1]+(size_t)layer*512*16,
      DTB[0]+(size_t)layer*512,    DTB[1]+(size_t)layer*512, dlt);
    // chunked scan
    k_scanA<<<dim3(NC,NB,2),512,0,stream>>>(dlt,xc,xdbl,
      AL[0]+(size_t)layer*512*16, AL[1]+(size_t)layer*512*16, sumA,sumS);
    k_scanB<<<dim3(NC,NB,2),512,0,stream>>>(dlt,xc,xdbl,xz,
      AL[0]+(size_t)layer*512*16, AL[1]+(size_t)layer*512*16,
      DP[0]+(size_t)layer*512,    DP[1]+(size_t)layer*512, sumA,sumS);
    // out_proj, both dirs: (4096x256) = y(4096x512, ld 1024) @ Wo^T
    k_gemmT<128,64,8,4><<<dim3(4,32,2),256,0,stream>>>(
      xz, xz+XZS, 1024,
      OW[0]+(size_t)layer*256*512, OW[1]+(size_t)layer*256*512, 512,256,
      outf, outb, 256);
    k_resln<<<NTOK,256,0,stream>>>(outf,outb,feat,GN,BNb);
  }
  k_head<<<NB,256,0,stream>>>(feat,WH1,BH1,WH2,BH2,(float*)d_out);
}

// Round 9
// 1142.442 us; speedup vs baseline: 3.0068x; 1.0876x over previous
//
#include <hip/hip_runtime.h>
#include <hip/hip_bf16.h>
#include <math.h>

typedef unsigned short u16;
typedef unsigned int u32;

#define NB 8
#define SL 512
#define DM 256
#define DI 512
#define NTOK (NB*SL)           // 4096 tokens
#define EPSF 1e-5f

// per-direction buffer strides
#define XZS (NTOK*2*DI)        // xz: (B,L,1024)
#define XCS (NTOK*DI)          // xc / dlt: (B,L,512)
#define XDS (NTOK*48)          // xdbl: (B,L,48)

// chunked scan
#define NC 16
#define CL 32

// ---------------- workspace (device globals) ----
__device__ __align__(16) float g_feat[NTOK*DM];
__device__ __align__(16) float g_xz  [2*XZS];
__device__ __align__(16) float g_xc  [2*XCS];
__device__ __align__(16) float g_xdbl[2*XDS];
__device__ __align__(16) float g_dlt [2*XCS];
__device__ __align__(16) float g_outf[NTOK*DM];
__device__ __align__(16) float g_outb[NTOK*DM];
__device__ __align__(16) float g_sumA[2*NB*NC*16*DI];
__device__ __align__(16) float g_sumS[2*NB*NC*16*DI];
__device__ __align__(16) float g_ent [2*NB*NC*16*DI];   // chunk entry states

// ---------------- helpers ----------------
__device__ __forceinline__ float siluf(float v){ return v/(1.0f+__expf(-v)); }
__device__ __forceinline__ float softplusf(float v){ return fmaxf(v,0.0f)+log1pf(__expf(-fabsf(v))); }

__device__ __forceinline__ void meanvar256(float v, float &mu, float &var, float* red){
  float s=v, q=v*v;
  #pragma unroll
  for (int off=32; off>0; off>>=1){ s+=__shfl_down(s,off); q+=__shfl_down(q,off); }
  int lane=threadIdx.x&63, w=threadIdx.x>>6;
  if (lane==0){ red[w]=s; red[4+w]=q; }
  __syncthreads();
  float st=red[0]+red[1]+red[2]+red[3];
  float qt=red[4]+red[5]+red[6]+red[7];
  mu=st*(1.0f/256.0f);
  var=qt*(1.0f/256.0f)-mu*mu;
  __syncthreads();
}

// ---------------- tokenize: 16 tokens/block, LDS-staged Wfus ----------------
#define TT 16
__global__ __launch_bounds__(256) void k_tokenize(
  const float* __restrict__ x, const float* __restrict__ embp, const float* __restrict__ embf,
  const float* __restrict__ embd, const float* __restrict__ Wlen, const float* __restrict__ blen,
  const float* __restrict__ Wiat, const float* __restrict__ biat, const float* __restrict__ Wfus,
  const float* __restrict__ bfus, const float* __restrict__ g, const float* __restrict__ bt,
  float* __restrict__ feat)
{
  int bl0=blockIdx.x*TT, t=threadIdx.x;
  __shared__ float cat[TT][136];
  __shared__ float sW[256*9];
  __shared__ float red[8];
  for (int f=t; f<TT*136; f+=256){
    int tok=f/136, j=f-tok*136, bl=bl0+tok;
    float cv;
    if      (j<32 ){ int p=min(255,max(0,(int)x[bl*5+0])); cv=embp[p*32+j]; }
    else if (j<64 ){ cv=fmaf(Wlen[j-32],x[bl*5+1],blen[j-32]); }
    else if (j<96 ){ int fl=min(63,max(0,(int)x[bl*5+2])); cv=embf[fl*32+(j-64)]; }
    else if (j<128){ cv=fmaf(Wiat[j-96],x[bl*5+3],biat[j-96]); }
    else           { int dd=min(1,max(0,(int)x[bl*5+4])); cv=embd[dd*8+(j-128)]; }
    cat[tok][j]=cv;
  }
  float acc[TT];
  float bf=bfus[t];
  #pragma unroll
  for (int tok=0;tok<TT;tok++) acc[tok]=bf;
  for (int kk0=0; kk0<136; kk0+=8){
    __syncthreads();
    for (int f=t; f<2048; f+=256){
      int tr=f>>3, j=f&7;
      sW[tr*9+j]=Wfus[tr*136+kk0+j];
    }
    __syncthreads();
    #pragma unroll
    for (int j=0;j<8;j++){
      float w=sW[t*9+j];
      #pragma unroll
      for (int tok=0;tok<TT;tok++) acc[tok]=fmaf(w,cat[tok][kk0+j],acc[tok]);
    }
  }
  __syncthreads();
  float gv=g[t], bv=bt[t];
  for (int tok=0;tok<TT;tok++){
    float mu,var; meanvar256(acc[tok],mu,var,red);
    feat[(size_t)(bl0+tok)*256+t]=fmaf((acc[tok]-mu)*rsqrtf(var+EPSF),gv,bv);
  }
}

// ---------------- templated fp32 GEMM, dual-direction via blockIdx.z ------------
template<int BM,int BN,int BK,int TM,int TN>
__global__ __launch_bounds__(256) void k_gemmT(
  const float* __restrict__ A0, const float* __restrict__ A1, int lda,
  const float* __restrict__ B0, const float* __restrict__ B1, int K, int N,
  float* __restrict__ C0, float* __restrict__ C1, int ldc)
{
  const float* A = blockIdx.z ? A1 : A0;
  const float* Bw= blockIdx.z ? B1 : B0;
  float*       C = blockIdx.z ? C1 : C0;
  __shared__ float As[BK][BM+4];
  __shared__ float Bs[BK][BN+4];
  int tid=threadIdx.x;
  int bm=blockIdx.y*BM, bn=blockIdx.x*BN;
  constexpr int NTX = BN/TN;
  int tx = tid % NTX, ty = tid / NTX;
  int tm0 = ty*TM, tn0 = tx*TN;
  float acc[TM][TN]={};
  constexpr int ASLOT = BM*BK/4;   // float4 slots
  constexpr int BSLOT = BN*BK/4;
  static_assert(ASLOT%256==0 && BSLOT%256==0, "loader shape");
  for (int k0=0;k0<K;k0+=BK){
    #pragma unroll
    for (int i=0;i<ASLOT/256;i++){
      int u = tid + i*256;
      int m = u/(BK/4); int kq = (u%(BK/4))*4;
      float4 v = *(const float4*)(A + (size_t)(bm+m)*lda + k0 + kq);
      As[kq+0][m]=v.x; As[kq+1][m]=v.y; As[kq+2][m]=v.z; As[kq+3][m]=v.w;
    }
    #pragma unroll
    for (int i=0;i<BSLOT/256;i++){
      int u = tid + i*256;
      int n = u/(BK/4); int kq = (u%(BK/4))*4;
      float4 v = make_float4(0.f,0.f,0.f,0.f);
      if (bn+n < N) v = *(const float4*)(Bw + (size_t)(bn+n)*K + k0 + kq);
      Bs[kq+0][n]=v.x; Bs[kq+1][n]=v.y; Bs[kq+2][n]=v.z; Bs[kq+3][n]=v.w;
    }
    __syncthreads();
    #pragma unroll
    for (int k=0;k<BK;k++){
      float a[TM], b[TN];
      #pragma unroll
      for (int i=0;i<TM;i+=4) *(float4*)&a[i] = *(const float4*)&As[k][tm0+i];
      #pragma unroll
      for (int j=0;j<TN;j+=4) *(float4*)&b[j] = *(const float4*)&Bs[k][tn0+j];
      #pragma unroll
      for (int i=0;i<TM;i++)
        #pragma unroll
        for (int j=0;j<TN;j++) acc[i][j]=fmaf(a[i],b[j],acc[i][j]);
    }
    __syncthreads();
  }
  #pragma unroll
  for (int i=0;i<TM;i++){
    int m=bm+tm0+i;
    #pragma unroll
    for (int j=0;j<TN;j+=4){
      int n=bn+tn0+j;
      if (n < N) *(float4*)(C + (size_t)m*ldc + n) = *(float4*)&acc[i][j];
    }
  }
}

// ---------------- x_proj split-K GEMM: C[m,0..47] += A[m,k]*Bw[n,k] -------------
// grid (KS=4, M/64, 2 dirs); atomicAdd into zeroed C.
__global__ __launch_bounds__(256) void k_gemmSK(
  const float* __restrict__ A0, const float* __restrict__ A1, int lda,
  const float* __restrict__ B0, const float* __restrict__ B1, int K,
  float* __restrict__ C0, float* __restrict__ C1, int ldc)
{
  int dir=blockIdx.z;
  const float* A = dir ? A1 : A0;
  const float* Bw= dir ? B1 : B0;
  float*       C = dir ? C1 : C0;
  int ks=blockIdx.x;
  int bm=blockIdx.y*64;
  __shared__ float As[16][68];
  __shared__ float Bs[16][52];
  int tid=threadIdx.x;
  int tx=tid%16, ty=tid/16;       // ty 0..15
  int tm0=ty*4, tn0=tx*3;
  float acc[4][3]={};
  int kbeg=ks*128, kend=kbeg+128;
  for (int k0=kbeg;k0<kend;k0+=16){
    { int m=tid>>2, kq=(tid&3)<<2;
      float4 v = *(const float4*)(A + (size_t)(bm+m)*lda + k0 + kq);
      As[kq+0][m]=v.x; As[kq+1][m]=v.y; As[kq+2][m]=v.z; As[kq+3][m]=v.w; }
    if (tid<192){ int n=tid>>2, kq=(tid&3)<<2;
      float4 v = *(const float4*)(Bw + (size_t)n*K + k0 + kq);
      Bs[kq+0][n]=v.x; Bs[kq+1][n]=v.y; Bs[kq+2][n]=v.z; Bs[kq+3][n]=v.w; }
    __syncthreads();
    #pragma unroll
    for (int k=0;k<16;k++){
      float4 a = *(const float4*)&As[k][tm0];
      float b0=Bs[k][tn0], b1=Bs[k][tn0+1], b2=Bs[k][tn0+2];
      acc[0][0]=fmaf(a.x,b0,acc[0][0]); acc[0][1]=fmaf(a.x,b1,acc[0][1]); acc[0][2]=fmaf(a.x,b2,acc[0][2]);
      acc[1][0]=fmaf(a.y,b0,acc[1][0]); acc[1][1]=fmaf(a.y,b1,acc[1][1]); acc[1][2]=fmaf(a.y,b2,acc[1][2]);
      acc[2][0]=fmaf(a.z,b0,acc[2][0]); acc[2][1]=fmaf(a.z,b1,acc[2][1]); acc[2][2]=fmaf(a.z,b2,acc[2][2]);
      acc[3][0]=fmaf(a.w,b0,acc[3][0]); acc[3][1]=fmaf(a.w,b1,acc[3][1]); acc[3][2]=fmaf(a.w,b2,acc[3][2]);
    }
    __syncthreads();
  }
  #pragma unroll
  for (int i=0;i<4;i++)
    #pragma unroll
    for (int j=0;j<3;j++)
      atomicAdd(&C[(size_t)(bm+tm0+i)*ldc + tn0+j], acc[i][j]);
}

// ---------------- depthwise causal conv4 + SiLU, both dirs ----------------
__global__ __launch_bounds__(256) void k_conv2(const float* __restrict__ xz,
  const float* __restrict__ cw0, const float* __restrict__ cw1,
  const float* __restrict__ cb0, const float* __restrict__ cb1,
  float* __restrict__ xc)
{
  int dir=blockIdx.y;
  const float* xzp = xz + (size_t)dir*XZS;
  float*       xcp = (float*)xc + (size_t)dir*XCS;
  const float* cw = dir?cw1:cw0;
  const float* cb = dir?cb1:cb0;
  int idx=blockIdx.x*256+threadIdx.x;
  int d=idx&511; int bl=idx>>9; int l=bl&511; int b=bl>>9;
  float acc=cb[d];
  #pragma unroll
  for (int k=0;k<4;k++){
    int lk = dir ? (l+3-k) : (l-3+k);
    if (lk>=0 && lk<512)
      acc=fmaf(cw[d*4+k], xzp[(((size_t)(b*512+lk))<<10)+d], acc);
  }
  xcp[idx]=siluf(acc);
}

// ---------------- delta = softplus(dt @ Wdt^T + bdt), both dirs ----------------
__global__ __launch_bounds__(256) void k_delta2(const float* __restrict__ xdbl,
  const float* __restrict__ W0, const float* __restrict__ W1,
  const float* __restrict__ b0, const float* __restrict__ b1,
  float* __restrict__ dlt)
{
  int dir=blockIdx.y;
  const float* xd = xdbl + (size_t)dir*XDS;
  float*       dl = dlt  + (size_t)dir*XCS;
  const float* Wdt = dir?W1:W0;
  const float* bdt = dir?b1:b0;
  int blk=blockIdx.x; int bl=blk>>1; int d=((blk&1)<<8)+threadIdx.x;
  __shared__ float sdt[16];
  if (threadIdx.x<16) sdt[threadIdx.x]=xd[bl*48+threadIdx.x];
  __syncthreads();
  float acc=bdt[d];
  #pragma unroll
  for (int r=0;r<16;r++) acc=fmaf(sdt[r],Wdt[d*16+r],acc);
  dl[bl*512+d]=softplusf(acc);
}

// ---------------- chunked selective scan -------------------
__global__ __launch_bounds__(512) void k_scanA(
  const float* __restrict__ dlt, const float* __restrict__ xc,
  const float* __restrict__ xdbl,
  const float* __restrict__ ALf, const float* __restrict__ ALb,
  float* __restrict__ sumA, float* __restrict__ sumS)
{
  int c=blockIdx.x, b=blockIdx.y, dir=blockIdx.z;
  int d=threadIdx.x;
  const float* AL = dir?ALb:ALf;
  const float* dl_p = dlt + (size_t)dir*XCS;
  const float* xc_p = xc  + (size_t)dir*XCS;
  const float* xd_p = xdbl+ (size_t)dir*XDS;
  __shared__ float sBC[CL][32];
  for (int f=d; f<CL*32; f+=512){
    int ll=f>>5, j=f&31;
    int l = dir ? (511-(c*CL+ll)) : (c*CL+ll);
    sBC[ll][j] = xd_p[((size_t)b*512+l)*48+16+j];
  }
  __syncthreads();
  float A[16];
  const float4* ALv = (const float4*)(AL + d*16);
  #pragma unroll
  for (int i=0;i<4;i++){
    float4 v = ALv[i];
    A[4*i+0]=-__expf(v.x); A[4*i+1]=-__expf(v.y);
    A[4*i+2]=-__expf(v.z); A[4*i+3]=-__expf(v.w);
  }
  float h[16], ap[16];
  #pragma unroll
  for (int s=0;s<16;s++){ h[s]=0.f; ap[s]=1.f; }
  for (int ll=0; ll<CL; ll++){
    int l = dir ? (511-(c*CL+ll)) : (c*CL+ll);
    size_t bl=(size_t)b*512+l;
    float dl = dl_p[bl*512+d];
    float xv = xc_p[bl*512+d];
    float du = dl*xv;
    #pragma unroll
    for (int s=0;s<16;s++){
      float a = __expf(dl*A[s]);
      h[s]=fmaf(a,h[s],du*sBC[ll][s]);
      ap[s]*=a;
    }
  }
  size_t base = ((((size_t)dir*NB+b)*NC+c)*16)*DI + d;
  #pragma unroll
  for (int s=0;s<16;s++){
    sumA[base + (size_t)s*DI] = ap[s];
    sumS[base + (size_t)s*DI] = h[s];
  }
}

// prefix over chunk summaries -> entry state per chunk
// grid (32, NB, 2): blockIdx.x = s*2 + dhalf; 256 threads = d within half
__global__ __launch_bounds__(256) void k_scanP(
  const float* __restrict__ sumA, const float* __restrict__ sumS,
  float* __restrict__ ent)
{
  int s=blockIdx.x>>1;
  int d=((blockIdx.x&1)<<8)+threadIdx.x;
  int b=blockIdx.y, dir=blockIdx.z;
  size_t stride_c = (size_t)16*DI;
  size_t base = (((size_t)dir*NB+b)*NC*16 + s)*DI + d;
  float h=0.f;
  for (int c=0;c<NC;c++){
    size_t off = base + (size_t)c*stride_c;
    ent[off] = h;
    h = fmaf(sumA[off], h, sumS[off]);
  }
}

__global__ __launch_bounds__(512) void k_scanB(
  const float* __restrict__ dlt, const float* __restrict__ xc,
  const float* __restrict__ xdbl, float* __restrict__ xz,
  const float* __restrict__ ALf, const float* __restrict__ ALb,
  const float* __restrict__ DPf, const float* __restrict__ DPb,
  const float* __restrict__ ent)
{
  int c=blockIdx.x, b=blockIdx.y, dir=blockIdx.z;
  int d=threadIdx.x;
  const float* AL = dir?ALb:ALf;
  const float* DP = dir?DPb:DPf;
  const float* dl_p = dlt + (size_t)dir*XCS;
  const float* xc_p = xc  + (size_t)dir*XCS;
  const float* xd_p = xdbl+ (size_t)dir*XDS;
  float*       xz_p = xz  + (size_t)dir*XZS;
  __shared__ float sBC[CL][32];
  for (int f=d; f<CL*32; f+=512){
    int ll=f>>5, j=f&31;
    int l = dir ? (511-(c*CL+ll)) : (c*CL+ll);
    sBC[ll][j] = xd_p[((size_t)b*512+l)*48+16+j];
  }
  __syncthreads();
  float A[16];
  const float4* ALv = (const float4*)(AL + d*16);
  #pragma unroll
  for (int i=0;i<4;i++){
    float4 v = ALv[i];
    A[4*i+0]=-__expf(v.x); A[4*i+1]=-__expf(v.y);
    A[4*i+2]=-__expf(v.z); A[4*i+3]=-__expf(v.w);
  }
  // entry state from prefix pass
  float h[16];
  size_t base = ((((size_t)dir*NB+b)*NC+c)*16)*DI + d;
  #pragma unroll
  for (int s=0;s<16;s++) h[s]=ent[base + (size_t)s*DI];
  float Dv = DP[d];
  for (int ll=0; ll<CL; ll++){
    int l = dir ? (511-(c*CL+ll)) : (c*CL+ll);
    size_t bl=(size_t)b*512+l;
    float dl = dl_p[bl*512+d];
    float xv = xc_p[bl*512+d];
    float zv = xz_p[(bl<<10)+512+d];
    float du = dl*xv;
    float y=0.f;
    #pragma unroll
    for (int s=0;s<16;s++){
      float a = __expf(dl*A[s]);
      h[s]=fmaf(a,h[s],du*sBC[ll][s]);
      y=fmaf(h[s],sBC[ll][16+s],y);
    }
    y=fmaf(xv,Dv,y);
    xz_p[(bl<<10)+d]=y*siluf(zv);
  }
}

// ---------------- residual + LayerNorm ----------------
__global__ __launch_bounds__(256) void k_resln(const float* __restrict__ of, const float* __restrict__ ob,
  float* __restrict__ feat, const float* __restrict__ g, const float* __restrict__ bb)
{
  int i=blockIdx.x*256+threadIdx.x;
  __shared__ float red[8];
  float v=of[i]+ob[i]+feat[i];
  float mu,var; meanvar256(v,mu,var,red);
  feat[i]=fmaf((v-mu)*rsqrtf(var+EPSF),g[threadIdx.x],bb[threadIdx.x]);
}

// ---------------- mean-pool + MLP head (fp32 output) ----------------
__global__ __launch_bounds__(256) void k_head(const float* __restrict__ feat, const float* __restrict__ W1,
  const float* __restrict__ bb1, const float* __restrict__ W2, const float* __restrict__ bb2,
  float* __restrict__ out)
{
  int b=blockIdx.x, t=threadIdx.x;
  __shared__ float sp[256], sh[256];
  float acc=0.0f;
  for (int l=0;l<512;l++) acc+=feat[((size_t)b*512+l)*256+t];
  sp[t]=acc*(1.0f/512.0f);
  __syncthreads();
  float a=bb1[t];
  for (int k=0;k<256;k++) a=fmaf(sp[k],W1[t*256+k],a);
  sh[t]=fmaxf(a,0.0f);
  __syncthreads();
  float o=bb2[t];
  for (int k=0;k<256;k++) o=fmaf(sh[k],W2[t*256+k],o);
  out[b*256+t]=o;
}

// ---------------- launch ----------------
extern "C" void kernel_launch(void* const* d_in, const int* in_sizes, int n_in,
                              void* d_out, int out_size, void* d_ws, size_t ws_size,
                              hipStream_t stream)
{
  (void)in_sizes; (void)n_in; (void)d_ws; (void)ws_size; (void)out_size;

  const float* X   =(const float*)d_in[0];
  const float* EMBP=(const float*)d_in[1];
  const float* EMBF=(const float*)d_in[2];
  const float* EMBD=(const float*)d_in[3];
  const float* WLEN=(const float*)d_in[4];
  const float* BLEN=(const float*)d_in[5];
  const float* WIAT=(const float*)d_in[6];
  const float* BIAT=(const float*)d_in[7];
  const float* WFUS=(const float*)d_in[8];
  const float* BFUS=(const float*)d_in[9];
  const float* GTOK=(const float*)d_in[10];
  const float* BTOK=(const float*)d_in[11];
  const float* GN  =(const float*)d_in[12];
  const float* BNb =(const float*)d_in[13];
  const float* WH1 =(const float*)d_in[14];
  const float* BH1 =(const float*)d_in[15];
  const float* WH2 =(const float*)d_in[16];
  const float* BH2 =(const float*)d_in[17];
  const float* INW[2]={(const float*)d_in[18],(const float*)d_in[27]};
  const float* CW [2]={(const float*)d_in[19],(const float*)d_in[28]};
  const float* CB [2]={(const float*)d_in[20],(const float*)d_in[29]};
  const float* XPW[2]={(const float*)d_in[21],(const float*)d_in[30]};
  const float* DTW[2]={(const float*)d_in[22],(const float*)d_in[31]};
  const float* DTB[2]={(const float*)d_in[23],(const float*)d_in[32]};
  const float* AL [2]={(const float*)d_in[24],(const float*)d_in[33]};
  const float* DP [2]={(const float*)d_in[25],(const float*)d_in[34]};
  const float* OW [2]={(const float*)d_in[26],(const float*)d_in[35]};

  float *feat,*xz,*xc,*xdbl,*dlt,*outf,*outb,*sumA,*sumS,*ent;
  hipGetSymbolAddress((void**)&feat, HIP_SYMBOL(g_feat));
  hipGetSymbolAddress((void**)&xz,   HIP_SYMBOL(g_xz));
  hipGetSymbolAddress((void**)&xc,   HIP_SYMBOL(g_xc));
  hipGetSymbolAddress((void**)&xdbl, HIP_SYMBOL(g_xdbl));
  hipGetSymbolAddress((void**)&dlt,  HIP_SYMBOL(g_dlt));
  hipGetSymbolAddress((void**)&outf, HIP_SYMBOL(g_outf));
  hipGetSymbolAddress((void**)&outb, HIP_SYMBOL(g_outb));
  hipGetSymbolAddress((void**)&sumA, HIP_SYMBOL(g_sumA));
  hipGetSymbolAddress((void**)&sumS, HIP_SYMBOL(g_sumS));
  hipGetSymbolAddress((void**)&ent,  HIP_SYMBOL(g_ent));

  k_tokenize<<<NTOK/TT,256,0,stream>>>(X,EMBP,EMBF,EMBD,WLEN,BLEN,WIAT,BIAT,WFUS,BFUS,GTOK,BTOK,feat);
  for (int layer=0; layer<4; layer++){
    // in_proj, both dirs: (4096x1024) = feat(4096x256) @ Wp^T   [1024 blocks]
    k_gemmT<128,64,32,8,4><<<dim3(16,32,2),256,0,stream>>>(
      feat,feat,256,
      INW[0]+(size_t)layer*1024*256, INW[1]+(size_t)layer*1024*256, 256,1024,
      xz, xz+XZS, 1024);
    // conv + silu, both dirs
    k_conv2<<<dim3(NTOK*DI/256,2),256,0,stream>>>(xz,
      CW[0]+(size_t)layer*512*4, CW[1]+(size_t)layer*512*4,
      CB[0]+(size_t)layer*512,   CB[1]+(size_t)layer*512, xc);
    // x_proj split-K: (4096x48) = xc(4096x512) @ Wx^T   [512 blocks, atomic]
    hipMemsetAsync(xdbl, 0, sizeof(float)*2*XDS, stream);
    k_gemmSK<<<dim3(4,64,2),256,0,stream>>>(
      xc, xc+XCS, 512,
      XPW[0]+(size_t)layer*48*512, XPW[1]+(size_t)layer*48*512, 512,
      xdbl, xdbl+XDS, 48);
    // delta, both dirs
    k_delta2<<<dim3(NTOK*2,2),256,0,stream>>>(xdbl,
      DTW[0]+(size_t)layer*512*16, DTW[1]+(size_t)layer*512*16,
      DTB[0]+(size_t)layer*512,    DTB[1]+(size_t)layer*512, dlt);
    // chunked scan: local summaries -> prefix -> apply
    k_scanA<<<dim3(NC,NB,2),512,0,stream>>>(dlt,xc,xdbl,
      AL[0]+(size_t)layer*512*16, AL[1]+(size_t)layer*512*16, sumA,sumS);
    k_scanP<<<dim3(32,NB,2),256,0,stream>>>(sumA,sumS,ent);
    k_scanB<<<dim3(NC,NB,2),512,0,stream>>>(dlt,xc,xdbl,xz,
      AL[0]+(size_t)layer*512*16, AL[1]+(size_t)layer*512*16,
      DP[0]+(size_t)layer*512,    DP[1]+(size_t)layer*512, ent);
    // out_proj, both dirs: (4096x256) = y(4096x512, ld 1024) @ Wo^T  [512 blocks]
    k_gemmT<64,64,16,4,4><<<dim3(4,64,2),256,0,stream>>>(
      xz, xz+XZS, 1024,
      OW[0]+(size_t)layer*256*512, OW[1]+(size_t)layer*256*512, 512,256,
      outf, outb, 256);
    k_resln<<<NTOK,256,0,stream>>>(outf,outb,feat,GN,BNb);
  }
  k_head<<<NB,256,0,stream>>>(feat,WH1,BH1,WH2,BH2,(float*)d_out);
}

// Round 10
// 1008.288 us; speedup vs baseline: 3.4068x; 1.1331x over previous
//
#include <hip/hip_runtime.h>
#include <hip/hip_bf16.h>
#include <math.h>

typedef unsigned short u16;
typedef unsigned int u32;
typedef __attribute__((ext_vector_type(8))) short short8;   // 8 bf16 (4 VGPRs)
typedef __attribute__((ext_vector_type(4))) float f32x4;    // MFMA acc

#define NB 8
#define SL 512
#define DM 256
#define DI 512
#define NTOK (NB*SL)           // 4096 tokens
#define EPSF 1e-5f

// per-direction buffer strides
#define XZS (NTOK*2*DI)        // xz: (B,L,1024)
#define XCS (NTOK*DI)          // xc / dlt / y: (B,L,512)
#define XDS (NTOK*48)          // xdbl: (B,L,48)

// chunked scan
#define NC 16
#define CL 32

// ---------------- workspace (device globals) ----
__device__ __align__(16) float g_feat[NTOK*DM];
__device__ __align__(16) float g_xz  [2*XZS];
__device__ __align__(16) float g_xc  [2*XCS];
__device__ __align__(16) float g_xdbl[2*XDS];
__device__ __align__(16) float g_dlt [2*XCS];
__device__ __align__(16) float g_outf[NTOK*DM];
__device__ __align__(16) float g_outb[NTOK*DM];
__device__ __align__(16) float g_sumA[2*NB*NC*16*DI];
__device__ __align__(16) float g_sumS[2*NB*NC*16*DI];
__device__ __align__(16) float g_ent [2*NB*NC*16*DI];
// bf16 hi/lo split buffers
__device__ __align__(16) u16 g_fh[NTOK*DM];          // feat hi
__device__ __align__(16) u16 g_fl[NTOK*DM];          // feat lo
__device__ __align__(16) u16 g_yh[2*XCS];            // gated y hi
__device__ __align__(16) u16 g_yl[2*XCS];            // gated y lo
__device__ __align__(16) u16 g_iwh[2*4*1024*DM];     // in_proj W hi
__device__ __align__(16) u16 g_iwl[2*4*1024*DM];
__device__ __align__(16) u16 g_owh[2*4*DM*DI];       // out_proj W hi
__device__ __align__(16) u16 g_owl[2*4*DM*DI];

// ---------------- helpers ----------------
__device__ __forceinline__ float siluf(float v){ return v/(1.0f+__expf(-v)); }
__device__ __forceinline__ float softplusf(float v){ return fmaxf(v,0.0f)+log1pf(__expf(-fabsf(v))); }
__device__ __forceinline__ float b2f(u16 u){ union { u32 i; float f; } v; v.i=((u32)u)<<16; return v.f; }
__device__ __forceinline__ u16 f2b(float f){ union { float f; u32 i; } v; v.f=f; u32 r=v.i+0x7fffu+((v.i>>16)&1u); return (u16)(r>>16); }
__device__ __forceinline__ void bsplit(float v, u16* h, u16* l){
  u16 hb=f2b(v); *h=hb; *l=f2b(v-b2f(hb));
}

__device__ __forceinline__ void meanvar256(float v, float &mu, float &var, float* red){
  float s=v, q=v*v;
  #pragma unroll
  for (int off=32; off>0; off>>=1){ s+=__shfl_down(s,off); q+=__shfl_down(q,off); }
  int lane=threadIdx.x&63, w=threadIdx.x>>6;
  if (lane==0){ red[w]=s; red[4+w]=q; }
  __syncthreads();
  float st=red[0]+red[1]+red[2]+red[3];
  float qt=red[4]+red[5]+red[6]+red[7];
  mu=st*(1.0f/256.0f);
  var=qt*(1.0f/256.0f)-mu*mu;
  __syncthreads();
}

// ---------------- fp32 -> bf16 hi/lo weight split ----------------
__global__ __launch_bounds__(256) void k_cvt(const float* __restrict__ src,
  u16* __restrict__ h, u16* __restrict__ l, int n)
{
  int i=blockIdx.x*256+threadIdx.x;
  if (i<n) bsplit(src[i], &h[i], &l[i]);
}

// ---------------- tokenize: 16 tokens/block, LDS-staged Wfus ----------------
#define TT 16
__global__ __launch_bounds__(256) void k_tokenize(
  const float* __restrict__ x, const float* __restrict__ embp, const float* __restrict__ embf,
  const float* __restrict__ embd, const float* __restrict__ Wlen, const float* __restrict__ blen,
  const float* __restrict__ Wiat, const float* __restrict__ biat, const float* __restrict__ Wfus,
  const float* __restrict__ bfus, const float* __restrict__ g, const float* __restrict__ bt,
  float* __restrict__ feat, u16* __restrict__ fh, u16* __restrict__ fl)
{
  int bl0=blockIdx.x*TT, t=threadIdx.x;
  __shared__ float cat[TT][136];
  __shared__ float sW[256*9];
  __shared__ float red[8];
  for (int f=t; f<TT*136; f+=256){
    int tok=f/136, j=f-tok*136, bl=bl0+tok;
    float cv;
    if      (j<32 ){ int p=min(255,max(0,(int)x[bl*5+0])); cv=embp[p*32+j]; }
    else if (j<64 ){ cv=fmaf(Wlen[j-32],x[bl*5+1],blen[j-32]); }
    else if (j<96 ){ int fl2=min(63,max(0,(int)x[bl*5+2])); cv=embf[fl2*32+(j-64)]; }
    else if (j<128){ cv=fmaf(Wiat[j-96],x[bl*5+3],biat[j-96]); }
    else           { int dd=min(1,max(0,(int)x[bl*5+4])); cv=embd[dd*8+(j-128)]; }
    cat[tok][j]=cv;
  }
  float acc[TT];
  float bf=bfus[t];
  #pragma unroll
  for (int tok=0;tok<TT;tok++) acc[tok]=bf;
  for (int kk0=0; kk0<136; kk0+=8){
    __syncthreads();
    for (int f=t; f<2048; f+=256){
      int tr=f>>3, j=f&7;
      sW[tr*9+j]=Wfus[tr*136+kk0+j];
    }
    __syncthreads();
    #pragma unroll
    for (int j=0;j<8;j++){
      float w=sW[t*9+j];
      #pragma unroll
      for (int tok=0;tok<TT;tok++) acc[tok]=fmaf(w,cat[tok][kk0+j],acc[tok]);
    }
  }
  __syncthreads();
  float gv=g[t], bv=bt[t];
  for (int tok=0;tok<TT;tok++){
    float mu,var; meanvar256(acc[tok],mu,var,red);
    float o=fmaf((acc[tok]-mu)*rsqrtf(var+EPSF),gv,bv);
    size_t idx=(size_t)(bl0+tok)*256+t;
    feat[idx]=o; bsplit(o,&fh[idx],&fl[idx]);
  }
}

// ---------------- MFMA GEMM (bf16 hi/lo split, fp32 acc) -----------------------
// C[m,n] = sum_k A[m,k]*B[n,k]; A,B pre-split into bf16 hi/lo, K-major.
// 64x64 block tile, 4 waves (2x2), each wave 32x32 = 2x2 mfma_16x16x32 tiles.
// LDS rows padded to 40 u16 (80 B) -> frag ds_read_b128 is 2-way (free).
__global__ __launch_bounds__(256) void k_gemmM(
  const u16* __restrict__ Ah0, const u16* __restrict__ Al0,
  const u16* __restrict__ Ah1, const u16* __restrict__ Al1, int lda,
  const u16* __restrict__ Bh0, const u16* __restrict__ Bl0,
  const u16* __restrict__ Bh1, const u16* __restrict__ Bl1, int K,
  float* __restrict__ C0, float* __restrict__ C1, int ldc)
{
  const u16* Ah = blockIdx.z?Ah1:Ah0; const u16* Al = blockIdx.z?Al1:Al0;
  const u16* Bh = blockIdx.z?Bh1:Bh0; const u16* Bl = blockIdx.z?Bl1:Bl0;
  float* C = blockIdx.z?C1:C0;
  __shared__ __align__(16) u16 sAh[64*40], sAl[64*40], sBh[64*40], sBl[64*40];
  int tid=threadIdx.x;
  int bm=blockIdx.y*64, bn=blockIdx.x*64;
  int wave=tid>>6, lane=tid&63;
  int quad=lane>>4, l16=lane&15;
  int wm=(wave&1)*32, wn=(wave>>1)*32;
  f32x4 acc[2][2]={};
  int r=tid>>2, sg=(tid&3)*8;   // stager: row 0..63, 8-u16 segment
  for (int k0=0;k0<K;k0+=32){
    *(uint4*)&sAh[r*40+sg] = *(const uint4*)(Ah + (size_t)(bm+r)*lda + k0 + sg);
    *(uint4*)&sAl[r*40+sg] = *(const uint4*)(Al + (size_t)(bm+r)*lda + k0 + sg);
    *(uint4*)&sBh[r*40+sg] = *(const uint4*)(Bh + (size_t)(bn+r)*K   + k0 + sg);
    *(uint4*)&sBl[r*40+sg] = *(const uint4*)(Bl + (size_t)(bn+r)*K   + k0 + sg);
    __syncthreads();
    short8 ah[2], al[2], bh[2], bl[2];
    #pragma unroll
    for (int t=0;t<2;t++){
      ah[t]=*(const short8*)&sAh[(wm+t*16+l16)*40+quad*8];
      al[t]=*(const short8*)&sAl[(wm+t*16+l16)*40+quad*8];
      bh[t]=*(const short8*)&sBh[(wn+t*16+l16)*40+quad*8];
      bl[t]=*(const short8*)&sBl[(wn+t*16+l16)*40+quad*8];
    }
    #pragma unroll
    for (int mt=0;mt<2;mt++)
      #pragma unroll
      for (int nt=0;nt<2;nt++){
        acc[mt][nt]=__builtin_amdgcn_mfma_f32_16x16x32_bf16(ah[mt],bh[nt],acc[mt][nt],0,0,0);
        acc[mt][nt]=__builtin_amdgcn_mfma_f32_16x16x32_bf16(al[mt],bh[nt],acc[mt][nt],0,0,0);
        acc[mt][nt]=__builtin_amdgcn_mfma_f32_16x16x32_bf16(ah[mt],bl[nt],acc[mt][nt],0,0,0);
      }
    __syncthreads();
  }
  #pragma unroll
  for (int mt=0;mt<2;mt++)
    #pragma unroll
    for (int nt=0;nt<2;nt++)
      #pragma unroll
      for (int reg=0;reg<4;reg++){
        int m=bm+wm+mt*16+quad*4+reg;
        int n=bn+wn+nt*16+l16;
        C[(size_t)m*ldc+n]=acc[mt][nt][reg];
      }
}

// ---------------- x_proj split-K GEMM (fp32, atomics) ----------------
__global__ __launch_bounds__(256) void k_gemmSK(
  const float* __restrict__ A0, const float* __restrict__ A1, int lda,
  const float* __restrict__ B0, const float* __restrict__ B1, int K,
  float* __restrict__ C0, float* __restrict__ C1, int ldc)
{
  int dir=blockIdx.z;
  const float* A = dir ? A1 : A0;
  const float* Bw= dir ? B1 : B0;
  float*       C = dir ? C1 : C0;
  int ks=blockIdx.x;
  int bm=blockIdx.y*64;
  __shared__ float As[16][68];
  __shared__ float Bs[16][52];
  int tid=threadIdx.x;
  int tx=tid%16, ty=tid/16;
  int tm0=ty*4, tn0=tx*3;
  float acc[4][3]={};
  int kbeg=ks*128, kend=kbeg+128;
  for (int k0=kbeg;k0<kend;k0+=16){
    { int m=tid>>2, kq=(tid&3)<<2;
      float4 v = *(const float4*)(A + (size_t)(bm+m)*lda + k0 + kq);
      As[kq+0][m]=v.x; As[kq+1][m]=v.y; As[kq+2][m]=v.z; As[kq+3][m]=v.w; }
    if (tid<192){ int n=tid>>2, kq=(tid&3)<<2;
      float4 v = *(const float4*)(Bw + (size_t)n*K + k0 + kq);
      Bs[kq+0][n]=v.x; Bs[kq+1][n]=v.y; Bs[kq+2][n]=v.z; Bs[kq+3][n]=v.w; }
    __syncthreads();
    #pragma unroll
    for (int k=0;k<16;k++){
      float4 a = *(const float4*)&As[k][tm0];
      float b0=Bs[k][tn0], b1=Bs[k][tn0+1], b2=Bs[k][tn0+2];
      acc[0][0]=fmaf(a.x,b0,acc[0][0]); acc[0][1]=fmaf(a.x,b1,acc[0][1]); acc[0][2]=fmaf(a.x,b2,acc[0][2]);
      acc[1][0]=fmaf(a.y,b0,acc[1][0]); acc[1][1]=fmaf(a.y,b1,acc[1][1]); acc[1][2]=fmaf(a.y,b2,acc[1][2]);
      acc[2][0]=fmaf(a.z,b0,acc[2][0]); acc[2][1]=fmaf(a.z,b1,acc[2][1]); acc[2][2]=fmaf(a.z,b2,acc[2][2]);
      acc[3][0]=fmaf(a.w,b0,acc[3][0]); acc[3][1]=fmaf(a.w,b1,acc[3][1]); acc[3][2]=fmaf(a.w,b2,acc[3][2]);
    }
    __syncthreads();
  }
  #pragma unroll
  for (int i=0;i<4;i++)
    #pragma unroll
    for (int j=0;j<3;j++)
      atomicAdd(&C[(size_t)(bm+tm0+i)*ldc + tn0+j], acc[i][j]);
}

// ---------------- depthwise causal conv4 + SiLU, both dirs ----------------
__global__ __launch_bounds__(256) void k_conv2(const float* __restrict__ xz,
  const float* __restrict__ cw0, const float* __restrict__ cw1,
  const float* __restrict__ cb0, const float* __restrict__ cb1,
  float* __restrict__ xc)
{
  int dir=blockIdx.y;
  const float* xzp = xz + (size_t)dir*XZS;
  float*       xcp = (float*)xc + (size_t)dir*XCS;
  const float* cw = dir?cw1:cw0;
  const float* cb = dir?cb1:cb0;
  int idx=blockIdx.x*256+threadIdx.x;
  int d=idx&511; int bl=idx>>9; int l=bl&511; int b=bl>>9;
  float acc=cb[d];
  #pragma unroll
  for (int k=0;k<4;k++){
    int lk = dir ? (l+3-k) : (l-3+k);
    if (lk>=0 && lk<512)
      acc=fmaf(cw[d*4+k], xzp[(((size_t)(b*512+lk))<<10)+d], acc);
  }
  xcp[idx]=siluf(acc);
}

// ---------------- delta = softplus(dt @ Wdt^T + bdt), both dirs ----------------
__global__ __launch_bounds__(256) void k_delta2(const float* __restrict__ xdbl,
  const float* __restrict__ W0, const float* __restrict__ W1,
  const float* __restrict__ b0, const float* __restrict__ b1,
  float* __restrict__ dlt)
{
  int dir=blockIdx.y;
  const float* xd = xdbl + (size_t)dir*XDS;
  float*       dl = dlt  + (size_t)dir*XCS;
  const float* Wdt = dir?W1:W0;
  const float* bdt = dir?b1:b0;
  int blk=blockIdx.x; int bl=blk>>1; int d=((blk&1)<<8)+threadIdx.x;
  __shared__ float sdt[16];
  if (threadIdx.x<16) sdt[threadIdx.x]=xd[bl*48+threadIdx.x];
  __syncthreads();
  float acc=bdt[d];
  #pragma unroll
  for (int r=0;r<16;r++) acc=fmaf(sdt[r],Wdt[d*16+r],acc);
  dl[bl*512+d]=softplusf(acc);
}

// ---------------- chunked selective scan -------------------
__global__ __launch_bounds__(512) void k_scanA(
  const float* __restrict__ dlt, const float* __restrict__ xc,
  const float* __restrict__ xdbl,
  const float* __restrict__ ALf, const float* __restrict__ ALb,
  float* __restrict__ sumA, float* __restrict__ sumS)
{
  int c=blockIdx.x, b=blockIdx.y, dir=blockIdx.z;
  int d=threadIdx.x;
  const float* AL = dir?ALb:ALf;
  const float* dl_p = dlt + (size_t)dir*XCS;
  const float* xc_p = xc  + (size_t)dir*XCS;
  const float* xd_p = xdbl+ (size_t)dir*XDS;
  __shared__ float sBC[CL][32];
  for (int f=d; f<CL*32; f+=512){
    int ll=f>>5, j=f&31;
    int l = dir ? (511-(c*CL+ll)) : (c*CL+ll);
    sBC[ll][j] = xd_p[((size_t)b*512+l)*48+16+j];
  }
  __syncthreads();
  float A[16];
  const float4* ALv = (const float4*)(AL + d*16);
  #pragma unroll
  for (int i=0;i<4;i++){
    float4 v = ALv[i];
    A[4*i+0]=-__expf(v.x); A[4*i+1]=-__expf(v.y);
    A[4*i+2]=-__expf(v.z); A[4*i+3]=-__expf(v.w);
  }
  float h[16], ap[16];
  #pragma unroll
  for (int s=0;s<16;s++){ h[s]=0.f; ap[s]=1.f; }
  for (int ll=0; ll<CL; ll++){
    int l = dir ? (511-(c*CL+ll)) : (c*CL+ll);
    size_t bl=(size_t)b*512+l;
    float dl = dl_p[bl*512+d];
    float xv = xc_p[bl*512+d];
    float du = dl*xv;
    #pragma unroll
    for (int s=0;s<16;s++){
      float a = __expf(dl*A[s]);
      h[s]=fmaf(a,h[s],du*sBC[ll][s]);
      ap[s]*=a;
    }
  }
  size_t base = ((((size_t)dir*NB+b)*NC+c)*16)*DI + d;
  #pragma unroll
  for (int s=0;s<16;s++){
    sumA[base + (size_t)s*DI] = ap[s];
    sumS[base + (size_t)s*DI] = h[s];
  }
}

__global__ __launch_bounds__(256) void k_scanP(
  const float* __restrict__ sumA, const float* __restrict__ sumS,
  float* __restrict__ ent)
{
  int s=blockIdx.x>>1;
  int d=((blockIdx.x&1)<<8)+threadIdx.x;
  int b=blockIdx.y, dir=blockIdx.z;
  size_t stride_c = (size_t)16*DI;
  size_t base = (((size_t)dir*NB+b)*NC*16 + s)*DI + d;
  float h=0.f;
  for (int c=0;c<NC;c++){
    size_t off = base + (size_t)c*stride_c;
    ent[off] = h;
    h = fmaf(sumA[off], h, sumS[off]);
  }
}

__global__ __launch_bounds__(512) void k_scanB(
  const float* __restrict__ dlt, const float* __restrict__ xc,
  const float* __restrict__ xdbl, const float* __restrict__ xz,
  const float* __restrict__ ALf, const float* __restrict__ ALb,
  const float* __restrict__ DPf, const float* __restrict__ DPb,
  const float* __restrict__ ent, u16* __restrict__ yh, u16* __restrict__ yl)
{
  int c=blockIdx.x, b=blockIdx.y, dir=blockIdx.z;
  int d=threadIdx.x;
  const float* AL = dir?ALb:ALf;
  const float* DP = dir?DPb:DPf;
  const float* dl_p = dlt + (size_t)dir*XCS;
  const float* xc_p = xc  + (size_t)dir*XCS;
  const float* xd_p = xdbl+ (size_t)dir*XDS;
  const float* xz_p = xz  + (size_t)dir*XZS;
  u16* yh_p = yh + (size_t)dir*XCS;
  u16* yl_p = yl + (size_t)dir*XCS;
  __shared__ float sBC[CL][32];
  for (int f=d; f<CL*32; f+=512){
    int ll=f>>5, j=f&31;
    int l = dir ? (511-(c*CL+ll)) : (c*CL+ll);
    sBC[ll][j] = xd_p[((size_t)b*512+l)*48+16+j];
  }
  __syncthreads();
  float A[16];
  const float4* ALv = (const float4*)(AL + d*16);
  #pragma unroll
  for (int i=0;i<4;i++){
    float4 v = ALv[i];
    A[4*i+0]=-__expf(v.x); A[4*i+1]=-__expf(v.y);
    A[4*i+2]=-__expf(v.z); A[4*i+3]=-__expf(v.w);
  }
  float h[16];
  size_t base = ((((size_t)dir*NB+b)*NC+c)*16)*DI + d;
  #pragma unroll
  for (int s=0;s<16;s++) h[s]=ent[base + (size_t)s*DI];
  float Dv = DP[d];
  for (int ll=0; ll<CL; ll++){
    int l = dir ? (511-(c*CL+ll)) : (c*CL+ll);
    size_t bl=(size_t)b*512+l;
    float dl = dl_p[bl*512+d];
    float xv = xc_p[bl*512+d];
    float zv = xz_p[(bl<<10)+512+d];
    float du = dl*xv;
    float y=0.f;
    #pragma unroll
    for (int s=0;s<16;s++){
      float a = __expf(dl*A[s]);
      h[s]=fmaf(a,h[s],du*sBC[ll][s]);
      y=fmaf(h[s],sBC[ll][16+s],y);
    }
    y=fmaf(xv,Dv,y);
    float gv = y*siluf(zv);
    bsplit(gv, &yh_p[bl*512+d], &yl_p[bl*512+d]);
  }
}

// ---------------- residual + LayerNorm (+ bf16 hi/lo emit) ----------------
__global__ __launch_bounds__(256) void k_resln(const float* __restrict__ of, const float* __restrict__ ob,
  float* __restrict__ feat, const float* __restrict__ g, const float* __restrict__ bb,
  u16* __restrict__ fh, u16* __restrict__ fl)
{
  int i=blockIdx.x*256+threadIdx.x;
  __shared__ float red[8];
  float v=of[i]+ob[i]+feat[i];
  float mu,var; meanvar256(v,mu,var,red);
  float o=fmaf((v-mu)*rsqrtf(var+EPSF),g[threadIdx.x],bb[threadIdx.x]);
  feat[i]=o; bsplit(o,&fh[i],&fl[i]);
}

// ---------------- mean-pool + MLP head (fp32 output) ----------------
__global__ __launch_bounds__(256) void k_head(const float* __restrict__ feat, const float* __restrict__ W1,
  const float* __restrict__ bb1, const float* __restrict__ W2, const float* __restrict__ bb2,
  float* __restrict__ out)
{
  int b=blockIdx.x, t=threadIdx.x;
  __shared__ float sp[256], sh[256];
  float acc=0.0f;
  for (int l=0;l<512;l++) acc+=feat[((size_t)b*512+l)*256+t];
  sp[t]=acc*(1.0f/512.0f);
  __syncthreads();
  float a=bb1[t];
  for (int k=0;k<256;k++) a=fmaf(sp[k],W1[t*256+k],a);
  sh[t]=fmaxf(a,0.0f);
  __syncthreads();
  float o=bb2[t];
  for (int k=0;k<256;k++) o=fmaf(sh[k],W2[t*256+k],o);
  out[b*256+t]=o;
}

// ---------------- launch ----------------
extern "C" void kernel_launch(void* const* d_in, const int* in_sizes, int n_in,
                              void* d_out, int out_size, void* d_ws, size_t ws_size,
                              hipStream_t stream)
{
  (void)in_sizes; (void)n_in; (void)d_ws; (void)ws_size; (void)out_size;

  const float* X   =(const float*)d_in[0];
  const float* EMBP=(const float*)d_in[1];
  const float* EMBF=(const float*)d_in[2];
  const float* EMBD=(const float*)d_in[3];
  const float* WLEN=(const float*)d_in[4];
  const float* BLEN=(const float*)d_in[5];
  const float* WIAT=(const float*)d_in[6];
  const float* BIAT=(const float*)d_in[7];
  const float* WFUS=(const float*)d_in[8];
  const float* BFUS=(const float*)d_in[9];
  const float* GTOK=(const float*)d_in[10];
  const float* BTOK=(const float*)d_in[11];
  const float* GN  =(const float*)d_in[12];
  const float* BNb =(const float*)d_in[13];
  const float* WH1 =(const float*)d_in[14];
  const float* BH1 =(const float*)d_in[15];
  const float* WH2 =(const float*)d_in[16];
  const float* BH2 =(const float*)d_in[17];
  const float* INW[2]={(const float*)d_in[18],(const float*)d_in[27]};
  const float* CW [2]={(const float*)d_in[19],(const float*)d_in[28]};
  const float* CB [2]={(const float*)d_in[20],(const float*)d_in[29]};
  const float* XPW[2]={(const float*)d_in[21],(const float*)d_in[30]};
  const float* DTW[2]={(const float*)d_in[22],(const float*)d_in[31]};
  const float* DTB[2]={(const float*)d_in[23],(const float*)d_in[32]};
  const float* AL [2]={(const float*)d_in[24],(const float*)d_in[33]};
  const float* DP [2]={(const float*)d_in[25],(const float*)d_in[34]};
  const float* OW [2]={(const float*)d_in[26],(const float*)d_in[35]};

  float *feat,*xz,*xc,*xdbl,*dlt,*outf,*outb,*sumA,*sumS,*ent;
  u16 *fh,*fl,*yh,*yl,*iwh,*iwl,*owh,*owl;
  hipGetSymbolAddress((void**)&feat, HIP_SYMBOL(g_feat));
  hipGetSymbolAddress((void**)&xz,   HIP_SYMBOL(g_xz));
  hipGetSymbolAddress((void**)&xc,   HIP_SYMBOL(g_xc));
  hipGetSymbolAddress((void**)&xdbl, HIP_SYMBOL(g_xdbl));
  hipGetSymbolAddress((void**)&dlt,  HIP_SYMBOL(g_dlt));
  hipGetSymbolAddress((void**)&outf, HIP_SYMBOL(g_outf));
  hipGetSymbolAddress((void**)&outb, HIP_SYMBOL(g_outb));
  hipGetSymbolAddress((void**)&sumA, HIP_SYMBOL(g_sumA));
  hipGetSymbolAddress((void**)&sumS, HIP_SYMBOL(g_sumS));
  hipGetSymbolAddress((void**)&ent,  HIP_SYMBOL(g_ent));
  hipGetSymbolAddress((void**)&fh,   HIP_SYMBOL(g_fh));
  hipGetSymbolAddress((void**)&fl,   HIP_SYMBOL(g_fl));
  hipGetSymbolAddress((void**)&yh,   HIP_SYMBOL(g_yh));
  hipGetSymbolAddress((void**)&yl,   HIP_SYMBOL(g_yl));
  hipGetSymbolAddress((void**)&iwh,  HIP_SYMBOL(g_iwh));
  hipGetSymbolAddress((void**)&iwl,  HIP_SYMBOL(g_iwl));
  hipGetSymbolAddress((void**)&owh,  HIP_SYMBOL(g_owh));
  hipGetSymbolAddress((void**)&owl,  HIP_SYMBOL(g_owl));

  // split weights to bf16 hi/lo (all layers at once; same work every call)
  const int NIW = 4*1024*DM, NOW = 4*DM*DI;
  for (int dir=0;dir<2;dir++){
    k_cvt<<<(NIW+255)/256,256,0,stream>>>(INW[dir], iwh+(size_t)dir*NIW, iwl+(size_t)dir*NIW, NIW);
    k_cvt<<<(NOW+255)/256,256,0,stream>>>(OW[dir],  owh+(size_t)dir*NOW, owl+(size_t)dir*NOW, NOW);
  }

  k_tokenize<<<NTOK/TT,256,0,stream>>>(X,EMBP,EMBF,EMBD,WLEN,BLEN,WIAT,BIAT,WFUS,BFUS,GTOK,BTOK,feat,fh,fl);
  for (int layer=0; layer<4; layer++){
    size_t iwoff = (size_t)layer*1024*DM;
    size_t owoff = (size_t)layer*DM*DI;
    // in_proj (MFMA): (4096x1024) = feat(4096x256) @ Wp^T
    k_gemmM<<<dim3(1024/64,4096/64,2),256,0,stream>>>(
      fh,fl,fh,fl,256,
      iwh+iwoff, iwl+iwoff, iwh+NIW+iwoff, iwl+NIW+iwoff, 256,
      xz, xz+XZS, 1024);
    // conv + silu, both dirs
    k_conv2<<<dim3(NTOK*DI/256,2),256,0,stream>>>(xz,
      CW[0]+(size_t)layer*512*4, CW[1]+(size_t)layer*512*4,
      CB[0]+(size_t)layer*512,   CB[1]+(size_t)layer*512, xc);
    // x_proj split-K (fp32): (4096x48) = xc(4096x512) @ Wx^T
    hipMemsetAsync(xdbl, 0, sizeof(float)*2*XDS, stream);
    k_gemmSK<<<dim3(4,64,2),256,0,stream>>>(
      xc, xc+XCS, 512,
      XPW[0]+(size_t)layer*48*512, XPW[1]+(size_t)layer*48*512, 512,
      xdbl, xdbl+XDS, 48);
    // delta, both dirs
    k_delta2<<<dim3(NTOK*2,2),256,0,stream>>>(xdbl,
      DTW[0]+(size_t)layer*512*16, DTW[1]+(size_t)layer*512*16,
      DTB[0]+(size_t)layer*512,    DTB[1]+(size_t)layer*512, dlt);
    // chunked scan
    k_scanA<<<dim3(NC,NB,2),512,0,stream>>>(dlt,xc,xdbl,
      AL[0]+(size_t)layer*512*16, AL[1]+(size_t)layer*512*16, sumA,sumS);
    k_scanP<<<dim3(32,NB,2),256,0,stream>>>(sumA,sumS,ent);
    k_scanB<<<dim3(NC,NB,2),512,0,stream>>>(dlt,xc,xdbl,xz,
      AL[0]+(size_t)layer*512*16, AL[1]+(size_t)layer*512*16,
      DP[0]+(size_t)layer*512,    DP[1]+(size_t)layer*512, ent, yh, yl);
    // out_proj (MFMA): (4096x256) = y(4096x512) @ Wo^T
    k_gemmM<<<dim3(256/64,4096/64,2),256,0,stream>>>(
      yh,yl, yh+XCS,yl+XCS, 512,
      owh+owoff, owl+owoff, owh+NOW+owoff, owl+NOW+owoff, 512,
      outf, outb, 256);
    k_resln<<<NTOK,256,0,stream>>>(outf,outb,feat,GN,BNb,fh,fl);
  }
  k_head<<<NB,256,0,stream>>>(feat,WH1,BH1,WH2,BH2,(float*)d_out);
}

// Round 11
// 987.771 us; speedup vs baseline: 3.4776x; 1.0208x over previous
//
#include <hip/hip_runtime.h>
#include <hip/hip_bf16.h>
#include <math.h>

typedef unsigned short u16;
typedef unsigned int u32;
typedef __attribute__((ext_vector_type(8))) short short8;   // 8 bf16 (4 VGPRs)
typedef __attribute__((ext_vector_type(4))) float f32x4;    // MFMA acc

#define NB 8
#define SL 512
#define DM 256
#define DI 512
#define NTOK (NB*SL)           // 4096 tokens
#define EPSF 1e-5f

// per-direction buffer strides
#define XZS (NTOK*2*DI)        // xz: (B,L,1024)
#define XCS (NTOK*DI)          // xc / y: (B,L,512)
#define XDS (NTOK*48)          // xdbl: (B,L,48)

// chunked scan
#define NC 16
#define CL 32

// ---------------- workspace (device globals) ----
__device__ __align__(16) float g_feat[NTOK*DM];
__device__ __align__(16) float g_xz  [2*XZS];
__device__ __align__(16) float g_xc  [2*XCS];
__device__ __align__(16) float g_xdbl[2*XDS];
__device__ __align__(16) float g_outf[NTOK*DM];
__device__ __align__(16) float g_outb[NTOK*DM];
__device__ __align__(16) float g_sumA[2*NB*NC*16*DI];
__device__ __align__(16) float g_sumS[2*NB*NC*16*DI];
__device__ __align__(16) float g_ent [2*NB*NC*16*DI];
__device__ __align__(16) float g_pool[NB*8*256];
// bf16 hi/lo split buffers
__device__ __align__(16) u16 g_fh[NTOK*DM];
__device__ __align__(16) u16 g_fl[NTOK*DM];
__device__ __align__(16) u16 g_yh[2*XCS];
__device__ __align__(16) u16 g_yl[2*XCS];
__device__ __align__(16) u16 g_iwh[2*4*1024*DM];
__device__ __align__(16) u16 g_iwl[2*4*1024*DM];
__device__ __align__(16) u16 g_owh[2*4*DM*DI];
__device__ __align__(16) u16 g_owl[2*4*DM*DI];

// ---------------- helpers ----------------
__device__ __forceinline__ float siluf(float v){ return v/(1.0f+__expf(-v)); }
__device__ __forceinline__ float softplusf(float v){ return fmaxf(v,0.0f)+log1pf(__expf(-fabsf(v))); }
__device__ __forceinline__ float b2f(u16 u){ union { u32 i; float f; } v; v.i=((u32)u)<<16; return v.f; }
__device__ __forceinline__ u16 f2b(float f){ union { float f; u32 i; } v; v.f=f; u32 r=v.i+0x7fffu+((v.i>>16)&1u); return (u16)(r>>16); }
__device__ __forceinline__ void bsplit(float v, u16* h, u16* l){
  u16 hb=f2b(v); *h=hb; *l=f2b(v-b2f(hb));
}

__device__ __forceinline__ void meanvar256(float v, float &mu, float &var, float* red){
  float s=v, q=v*v;
  #pragma unroll
  for (int off=32; off>0; off>>=1){ s+=__shfl_down(s,off); q+=__shfl_down(q,off); }
  int lane=threadIdx.x&63, w=threadIdx.x>>6;
  if (lane==0){ red[w]=s; red[4+w]=q; }
  __syncthreads();
  float st=red[0]+red[1]+red[2]+red[3];
  float qt=red[4]+red[5]+red[6]+red[7];
  mu=st*(1.0f/256.0f);
  var=qt*(1.0f/256.0f)-mu*mu;
  __syncthreads();
}

// ---------------- fp32 -> bf16 hi/lo weight split, both dirs ----------------
__global__ __launch_bounds__(256) void k_cvt2(const float* __restrict__ s0, const float* __restrict__ s1,
  u16* __restrict__ h, u16* __restrict__ l, int n)
{
  int dir=blockIdx.y;
  const float* s = dir?s1:s0;
  int i=blockIdx.x*256+threadIdx.x;
  if (i<n) bsplit(s[i], &h[(size_t)dir*n+i], &l[(size_t)dir*n+i]);
}

// ---------------- tokenize: 4 tokens/block (1024 blocks), LDS-staged Wfus -------
#define TT 4
__global__ __launch_bounds__(256) void k_tokenize(
  const float* __restrict__ x, const float* __restrict__ embp, const float* __restrict__ embf,
  const float* __restrict__ embd, const float* __restrict__ Wlen, const float* __restrict__ blen,
  const float* __restrict__ Wiat, const float* __restrict__ biat, const float* __restrict__ Wfus,
  const float* __restrict__ bfus, const float* __restrict__ g, const float* __restrict__ bt,
  float* __restrict__ feat, u16* __restrict__ fh, u16* __restrict__ fl)
{
  int bl0=blockIdx.x*TT, t=threadIdx.x;
  __shared__ float cat[TT][136];
  __shared__ float sW[256*9];
  __shared__ float red[8];
  for (int f=t; f<TT*136; f+=256){
    int tok=f/136, j=f-tok*136, bl=bl0+tok;
    float cv;
    if      (j<32 ){ int p=min(255,max(0,(int)x[bl*5+0])); cv=embp[p*32+j]; }
    else if (j<64 ){ cv=fmaf(Wlen[j-32],x[bl*5+1],blen[j-32]); }
    else if (j<96 ){ int fl2=min(63,max(0,(int)x[bl*5+2])); cv=embf[fl2*32+(j-64)]; }
    else if (j<128){ cv=fmaf(Wiat[j-96],x[bl*5+3],biat[j-96]); }
    else           { int dd=min(1,max(0,(int)x[bl*5+4])); cv=embd[dd*8+(j-128)]; }
    cat[tok][j]=cv;
  }
  float acc[TT];
  float bf=bfus[t];
  #pragma unroll
  for (int tok=0;tok<TT;tok++) acc[tok]=bf;
  for (int kk0=0; kk0<136; kk0+=8){
    __syncthreads();
    for (int f=t; f<2048; f+=256){
      int tr=f>>3, j=f&7;
      sW[tr*9+j]=Wfus[tr*136+kk0+j];
    }
    __syncthreads();
    #pragma unroll
    for (int j=0;j<8;j++){
      float w=sW[t*9+j];
      #pragma unroll
      for (int tok=0;tok<TT;tok++) acc[tok]=fmaf(w,cat[tok][kk0+j],acc[tok]);
    }
  }
  __syncthreads();
  float gv=g[t], bv=bt[t];
  #pragma unroll
  for (int tok=0;tok<TT;tok++){
    float mu,var; meanvar256(acc[tok],mu,var,red);
    float o=fmaf((acc[tok]-mu)*rsqrtf(var+EPSF),gv,bv);
    size_t idx=(size_t)(bl0+tok)*256+t;
    feat[idx]=o; bsplit(o,&fh[idx],&fl[idx]);
  }
}

// ---------------- MFMA GEMM (bf16 hi/lo split, fp32 acc) -----------------------
__global__ __launch_bounds__(256) void k_gemmM(
  const u16* __restrict__ Ah0, const u16* __restrict__ Al0,
  const u16* __restrict__ Ah1, const u16* __restrict__ Al1, int lda,
  const u16* __restrict__ Bh0, const u16* __restrict__ Bl0,
  const u16* __restrict__ Bh1, const u16* __restrict__ Bl1, int K,
  float* __restrict__ C0, float* __restrict__ C1, int ldc)
{
  const u16* Ah = blockIdx.z?Ah1:Ah0; const u16* Al = blockIdx.z?Al1:Al0;
  const u16* Bh = blockIdx.z?Bh1:Bh0; const u16* Bl = blockIdx.z?Bl1:Bl0;
  float* C = blockIdx.z?C1:C0;
  __shared__ __align__(16) u16 sAh[64*40], sAl[64*40], sBh[64*40], sBl[64*40];
  int tid=threadIdx.x;
  int bm=blockIdx.y*64, bn=blockIdx.x*64;
  int wave=tid>>6, lane=tid&63;
  int quad=lane>>4, l16=lane&15;
  int wm=(wave&1)*32, wn=(wave>>1)*32;
  f32x4 acc[2][2]={};
  int r=tid>>2, sg=(tid&3)*8;
  for (int k0=0;k0<K;k0+=32){
    *(uint4*)&sAh[r*40+sg] = *(const uint4*)(Ah + (size_t)(bm+r)*lda + k0 + sg);
    *(uint4*)&sAl[r*40+sg] = *(const uint4*)(Al + (size_t)(bm+r)*lda + k0 + sg);
    *(uint4*)&sBh[r*40+sg] = *(const uint4*)(Bh + (size_t)(bn+r)*K   + k0 + sg);
    *(uint4*)&sBl[r*40+sg] = *(const uint4*)(Bl + (size_t)(bn+r)*K   + k0 + sg);
    __syncthreads();
    short8 ah[2], al[2], bh[2], bl[2];
    #pragma unroll
    for (int t=0;t<2;t++){
      ah[t]=*(const short8*)&sAh[(wm+t*16+l16)*40+quad*8];
      al[t]=*(const short8*)&sAl[(wm+t*16+l16)*40+quad*8];
      bh[t]=*(const short8*)&sBh[(wn+t*16+l16)*40+quad*8];
      bl[t]=*(const short8*)&sBl[(wn+t*16+l16)*40+quad*8];
    }
    #pragma unroll
    for (int mt=0;mt<2;mt++)
      #pragma unroll
      for (int nt=0;nt<2;nt++){
        acc[mt][nt]=__builtin_amdgcn_mfma_f32_16x16x32_bf16(ah[mt],bh[nt],acc[mt][nt],0,0,0);
        acc[mt][nt]=__builtin_amdgcn_mfma_f32_16x16x32_bf16(al[mt],bh[nt],acc[mt][nt],0,0,0);
        acc[mt][nt]=__builtin_amdgcn_mfma_f32_16x16x32_bf16(ah[mt],bl[nt],acc[mt][nt],0,0,0);
      }
    __syncthreads();
  }
  #pragma unroll
  for (int mt=0;mt<2;mt++)
    #pragma unroll
    for (int nt=0;nt<2;nt++)
      #pragma unroll
      for (int reg=0;reg<4;reg++){
        int m=bm+wm+mt*16+quad*4+reg;
        int n=bn+wn+nt*16+l16;
        C[(size_t)m*ldc+n]=acc[mt][nt][reg];
      }
}

// ---------------- x_proj split-K GEMM (fp32, atomics) ----------------
__global__ __launch_bounds__(256) void k_gemmSK(
  const float* __restrict__ A0, const float* __restrict__ A1, int lda,
  const float* __restrict__ B0, const float* __restrict__ B1, int K,
  float* __restrict__ C0, float* __restrict__ C1, int ldc)
{
  int dir=blockIdx.z;
  const float* A = dir ? A1 : A0;
  const float* Bw= dir ? B1 : B0;
  float*       C = dir ? C1 : C0;
  int ks=blockIdx.x;
  int bm=blockIdx.y*64;
  __shared__ float As[16][68];
  __shared__ float Bs[16][52];
  int tid=threadIdx.x;
  int tx=tid%16, ty=tid/16;
  int tm0=ty*4, tn0=tx*3;
  float acc[4][3]={};
  int kbeg=ks*128, kend=kbeg+128;
  for (int k0=kbeg;k0<kend;k0+=16){
    { int m=tid>>2, kq=(tid&3)<<2;
      float4 v = *(const float4*)(A + (size_t)(bm+m)*lda + k0 + kq);
      As[kq+0][m]=v.x; As[kq+1][m]=v.y; As[kq+2][m]=v.z; As[kq+3][m]=v.w; }
    if (tid<192){ int n=tid>>2, kq=(tid&3)<<2;
      float4 v = *(const float4*)(Bw + (size_t)n*K + k0 + kq);
      Bs[kq+0][n]=v.x; Bs[kq+1][n]=v.y; Bs[kq+2][n]=v.z; Bs[kq+3][n]=v.w; }
    __syncthreads();
    #pragma unroll
    for (int k=0;k<16;k++){
      float4 a = *(const float4*)&As[k][tm0];
      float b0=Bs[k][tn0], b1=Bs[k][tn0+1], b2=Bs[k][tn0+2];
      acc[0][0]=fmaf(a.x,b0,acc[0][0]); acc[0][1]=fmaf(a.x,b1,acc[0][1]); acc[0][2]=fmaf(a.x,b2,acc[0][2]);
      acc[1][0]=fmaf(a.y,b0,acc[1][0]); acc[1][1]=fmaf(a.y,b1,acc[1][1]); acc[1][2]=fmaf(a.y,b2,acc[1][2]);
      acc[2][0]=fmaf(a.z,b0,acc[2][0]); acc[2][1]=fmaf(a.z,b1,acc[2][1]); acc[2][2]=fmaf(a.z,b2,acc[2][2]);
      acc[3][0]=fmaf(a.w,b0,acc[3][0]); acc[3][1]=fmaf(a.w,b1,acc[3][1]); acc[3][2]=fmaf(a.w,b2,acc[3][2]);
    }
    __syncthreads();
  }
  #pragma unroll
  for (int i=0;i<4;i++)
    #pragma unroll
    for (int j=0;j<3;j++)
      atomicAdd(&C[(size_t)(bm+tm0+i)*ldc + tn0+j], acc[i][j]);
}

// ---------------- depthwise causal conv4 + SiLU, both dirs ----------------
__global__ __launch_bounds__(256) void k_conv2(const float* __restrict__ xz,
  const float* __restrict__ cw0, const float* __restrict__ cw1,
  const float* __restrict__ cb0, const float* __restrict__ cb1,
  float* __restrict__ xc)
{
  int dir=blockIdx.y;
  const float* xzp = xz + (size_t)dir*XZS;
  float*       xcp = (float*)xc + (size_t)dir*XCS;
  const float* cw = dir?cw1:cw0;
  const float* cb = dir?cb1:cb0;
  int idx=blockIdx.x*256+threadIdx.x;
  int d=idx&511; int bl=idx>>9; int l=bl&511; int b=bl>>9;
  float acc=cb[d];
  #pragma unroll
  for (int k=0;k<4;k++){
    int lk = dir ? (l+3-k) : (l-3+k);
    if (lk>=0 && lk<512)
      acc=fmaf(cw[d*4+k], xzp[(((size_t)(b*512+lk))<<10)+d], acc);
  }
  xcp[idx]=siluf(acc);
}

// ---------------- chunked selective scan (delta fused on the fly) ---------------
// sBC[ll][0..15]=dt, [16..31]=B, [32..47]=C. Per-thread Wdt row (16 regs) + bias.
__global__ __launch_bounds__(512) void k_scanA(
  const float* __restrict__ xc, const float* __restrict__ xdbl,
  const float* __restrict__ ALf, const float* __restrict__ ALb,
  const float* __restrict__ Wdtf, const float* __restrict__ Wdtb,
  const float* __restrict__ bdtf, const float* __restrict__ bdtb,
  float* __restrict__ sumA, float* __restrict__ sumS)
{
  int c=blockIdx.x, b=blockIdx.y, dir=blockIdx.z;
  int d=threadIdx.x;
  const float* AL  = dir?ALb:ALf;
  const float* Wdt = dir?Wdtb:Wdtf;
  const float* bdt = dir?bdtb:bdtf;
  const float* xc_p = xc  + (size_t)dir*XCS;
  const float* xd_p = xdbl+ (size_t)dir*XDS;
  __shared__ float sBC[CL][48];
  for (int f=d; f<CL*48; f+=512){
    int ll=f/48, j=f-ll*48;
    int l = dir ? (511-(c*CL+ll)) : (c*CL+ll);
    sBC[ll][j] = xd_p[((size_t)b*512+l)*48+j];
  }
  __syncthreads();
  float A[16], W[16];
  const float4* ALv = (const float4*)(AL + d*16);
  const float4* Wv  = (const float4*)(Wdt + d*16);
  #pragma unroll
  for (int i=0;i<4;i++){
    float4 v = ALv[i];
    A[4*i+0]=-__expf(v.x); A[4*i+1]=-__expf(v.y);
    A[4*i+2]=-__expf(v.z); A[4*i+3]=-__expf(v.w);
    float4 w = Wv[i];
    W[4*i+0]=w.x; W[4*i+1]=w.y; W[4*i+2]=w.z; W[4*i+3]=w.w;
  }
  float bd = bdt[d];
  float h[16], ap[16];
  #pragma unroll
  for (int s=0;s<16;s++){ h[s]=0.f; ap[s]=1.f; }
  for (int ll=0; ll<CL; ll++){
    int l = dir ? (511-(c*CL+ll)) : (c*CL+ll);
    size_t bl=(size_t)b*512+l;
    float dt=bd;
    #pragma unroll
    for (int r2=0;r2<16;r2++) dt=fmaf(sBC[ll][r2],W[r2],dt);
    float dl = softplusf(dt);
    float xv = xc_p[bl*512+d];
    float du = dl*xv;
    #pragma unroll
    for (int s=0;s<16;s++){
      float a = __expf(dl*A[s]);
      h[s]=fmaf(a,h[s],du*sBC[ll][16+s]);
      ap[s]*=a;
    }
  }
  size_t base = ((((size_t)dir*NB+b)*NC+c)*16)*DI + d;
  #pragma unroll
  for (int s=0;s<16;s++){
    sumA[base + (size_t)s*DI] = ap[s];
    sumS[base + (size_t)s*DI] = h[s];
  }
}

__global__ __launch_bounds__(256) void k_scanP(
  const float* __restrict__ sumA, const float* __restrict__ sumS,
  float* __restrict__ ent)
{
  int s=blockIdx.x>>1;
  int d=((blockIdx.x&1)<<8)+threadIdx.x;
  int b=blockIdx.y, dir=blockIdx.z;
  size_t stride_c = (size_t)16*DI;
  size_t base = (((size_t)dir*NB+b)*NC*16 + s)*DI + d;
  float h=0.f;
  for (int c=0;c<NC;c++){
    size_t off = base + (size_t)c*stride_c;
    ent[off] = h;
    h = fmaf(sumA[off], h, sumS[off]);
  }
}

__global__ __launch_bounds__(512) void k_scanB(
  const float* __restrict__ xc, const float* __restrict__ xdbl,
  const float* __restrict__ xz,
  const float* __restrict__ ALf, const float* __restrict__ ALb,
  const float* __restrict__ Wdtf, const float* __restrict__ Wdtb,
  const float* __restrict__ bdtf, const float* __restrict__ bdtb,
  const float* __restrict__ DPf, const float* __restrict__ DPb,
  const float* __restrict__ ent, u16* __restrict__ yh, u16* __restrict__ yl)
{
  int c=blockIdx.x, b=blockIdx.y, dir=blockIdx.z;
  int d=threadIdx.x;
  const float* AL  = dir?ALb:ALf;
  const float* Wdt = dir?Wdtb:Wdtf;
  const float* bdt = dir?bdtb:bdtf;
  const float* DP  = dir?DPb:DPf;
  const float* xc_p = xc  + (size_t)dir*XCS;
  const float* xd_p = xdbl+ (size_t)dir*XDS;
  const float* xz_p = xz  + (size_t)dir*XZS;
  u16* yh_p = yh + (size_t)dir*XCS;
  u16* yl_p = yl + (size_t)dir*XCS;
  __shared__ float sBC[CL][48];
  for (int f=d; f<CL*48; f+=512){
    int ll=f/48, j=f-ll*48;
    int l = dir ? (511-(c*CL+ll)) : (c*CL+ll);
    sBC[ll][j] = xd_p[((size_t)b*512+l)*48+j];
  }
  __syncthreads();
  float A[16], W[16];
  const float4* ALv = (const float4*)(AL + d*16);
  const float4* Wv  = (const float4*)(Wdt + d*16);
  #pragma unroll
  for (int i=0;i<4;i++){
    float4 v = ALv[i];
    A[4*i+0]=-__expf(v.x); A[4*i+1]=-__expf(v.y);
    A[4*i+2]=-__expf(v.z); A[4*i+3]=-__expf(v.w);
    float4 w = Wv[i];
    W[4*i+0]=w.x; W[4*i+1]=w.y; W[4*i+2]=w.z; W[4*i+3]=w.w;
  }
  float bd = bdt[d];
  float h[16];
  size_t base = ((((size_t)dir*NB+b)*NC+c)*16)*DI + d;
  #pragma unroll
  for (int s=0;s<16;s++) h[s]=ent[base + (size_t)s*DI];
  float Dv = DP[d];
  for (int ll=0; ll<CL; ll++){
    int l = dir ? (511-(c*CL+ll)) : (c*CL+ll);
    size_t bl=(size_t)b*512+l;
    float dt=bd;
    #pragma unroll
    for (int r2=0;r2<16;r2++) dt=fmaf(sBC[ll][r2],W[r2],dt);
    float dl = softplusf(dt);
    float xv = xc_p[bl*512+d];
    float zv = xz_p[(bl<<10)+512+d];
    float du = dl*xv;
    float y=0.f;
    #pragma unroll
    for (int s=0;s<16;s++){
      float a = __expf(dl*A[s]);
      h[s]=fmaf(a,h[s],du*sBC[ll][16+s]);
      y=fmaf(h[s],sBC[ll][32+s],y);
    }
    y=fmaf(xv,Dv,y);
    float gv = y*siluf(zv);
    bsplit(gv, &yh_p[bl*512+d], &yl_p[bl*512+d]);
  }
}

// ---------------- residual + LayerNorm (+ bf16 hi/lo emit) ----------------
__global__ __launch_bounds__(256) void k_resln(const float* __restrict__ of, const float* __restrict__ ob,
  float* __restrict__ feat, const float* __restrict__ g, const float* __restrict__ bb,
  u16* __restrict__ fh, u16* __restrict__ fl)
{
  int i=blockIdx.x*256+threadIdx.x;
  __shared__ float red[8];
  float v=of[i]+ob[i]+feat[i];
  float mu,var; meanvar256(v,mu,var,red);
  float o=fmaf((v-mu)*rsqrtf(var+EPSF),g[threadIdx.x],bb[threadIdx.x]);
  feat[i]=o; bsplit(o,&fh[i],&fl[i]);
}

// ---------------- two-stage mean-pool + MLP head ----------------
__global__ __launch_bounds__(256) void k_pool(const float* __restrict__ feat, float* __restrict__ pool)
{
  int seg=blockIdx.x, b=blockIdx.y, t=threadIdx.x;
  float acc=0.f;
  for (int l=seg*64;l<seg*64+64;l++) acc+=feat[((size_t)b*512+l)*256+t];
  pool[((size_t)b*8+seg)*256+t]=acc;
}

__global__ __launch_bounds__(256) void k_head(const float* __restrict__ pool, const float* __restrict__ W1,
  const float* __restrict__ bb1, const float* __restrict__ W2, const float* __restrict__ bb2,
  float* __restrict__ out)
{
  int b=blockIdx.x, t=threadIdx.x;
  __shared__ float sp[256], sh[256];
  float acc=0.0f;
  #pragma unroll
  for (int seg=0;seg<8;seg++) acc+=pool[((size_t)b*8+seg)*256+t];
  sp[t]=acc*(1.0f/512.0f);
  __syncthreads();
  float a=bb1[t];
  for (int k=0;k<256;k++) a=fmaf(sp[k],W1[t*256+k],a);
  sh[t]=fmaxf(a,0.0f);
  __syncthreads();
  float o=bb2[t];
  for (int k=0;k<256;k++) o=fmaf(sh[k],W2[t*256+k],o);
  out[b*256+t]=o;
}

// ---------------- launch ----------------
extern "C" void kernel_launch(void* const* d_in, const int* in_sizes, int n_in,
                              void* d_out, int out_size, void* d_ws, size_t ws_size,
                              hipStream_t stream)
{
  (void)in_sizes; (void)n_in; (void)d_ws; (void)ws_size; (void)out_size;

  const float* X   =(const float*)d_in[0];
  const float* EMBP=(const float*)d_in[1];
  const float* EMBF=(const float*)d_in[2];
  const float* EMBD=(const float*)d_in[3];
  const float* WLEN=(const float*)d_in[4];
  const float* BLEN=(const float*)d_in[5];
  const float* WIAT=(const float*)d_in[6];
  const float* BIAT=(const float*)d_in[7];
  const float* WFUS=(const float*)d_in[8];
  const float* BFUS=(const float*)d_in[9];
  const float* GTOK=(const float*)d_in[10];
  const float* BTOK=(const float*)d_in[11];
  const float* GN  =(const float*)d_in[12];
  const float* BNb =(const float*)d_in[13];
  const float* WH1 =(const float*)d_in[14];
  const float* BH1 =(const float*)d_in[15];
  const float* WH2 =(const float*)d_in[16];
  const float* BH2 =(const float*)d_in[17];
  const float* INW[2]={(const float*)d_in[18],(const float*)d_in[27]};
  const float* CW [2]={(const float*)d_in[19],(const float*)d_in[28]};
  const float* CB [2]={(const float*)d_in[20],(const float*)d_in[29]};
  const float* XPW[2]={(const float*)d_in[21],(const float*)d_in[30]};
  const float* DTW[2]={(const float*)d_in[22],(const float*)d_in[31]};
  const float* DTB[2]={(const float*)d_in[23],(const float*)d_in[32]};
  const float* AL [2]={(const float*)d_in[24],(const float*)d_in[33]};
  const float* DP [2]={(const float*)d_in[25],(const float*)d_in[34]};
  const float* OW [2]={(const float*)d_in[26],(const float*)d_in[35]};

  float *feat,*xz,*xc,*xdbl,*outf,*outb,*sumA,*sumS,*ent,*pool;
  u16 *fh,*fl,*yh,*yl,*iwh,*iwl,*owh,*owl;
  hipGetSymbolAddress((void**)&feat, HIP_SYMBOL(g_feat));
  hipGetSymbolAddress((void**)&xz,   HIP_SYMBOL(g_xz));
  hipGetSymbolAddress((void**)&xc,   HIP_SYMBOL(g_xc));
  hipGetSymbolAddress((void**)&xdbl, HIP_SYMBOL(g_xdbl));
  hipGetSymbolAddress((void**)&outf, HIP_SYMBOL(g_outf));
  hipGetSymbolAddress((void**)&outb, HIP_SYMBOL(g_outb));
  hipGetSymbolAddress((void**)&sumA, HIP_SYMBOL(g_sumA));
  hipGetSymbolAddress((void**)&sumS, HIP_SYMBOL(g_sumS));
  hipGetSymbolAddress((void**)&ent,  HIP_SYMBOL(g_ent));
  hipGetSymbolAddress((void**)&pool, HIP_SYMBOL(g_pool));
  hipGetSymbolAddress((void**)&fh,   HIP_SYMBOL(g_fh));
  hipGetSymbolAddress((void**)&fl,   HIP_SYMBOL(g_fl));
  hipGetSymbolAddress((void**)&yh,   HIP_SYMBOL(g_yh));
  hipGetSymbolAddress((void**)&yl,   HIP_SYMBOL(g_yl));
  hipGetSymbolAddress((void**)&iwh,  HIP_SYMBOL(g_iwh));
  hipGetSymbolAddress((void**)&iwl,  HIP_SYMBOL(g_iwl));
  hipGetSymbolAddress((void**)&owh,  HIP_SYMBOL(g_owh));
  hipGetSymbolAddress((void**)&owl,  HIP_SYMBOL(g_owl));

  // split weights to bf16 hi/lo (both dirs per dispatch)
  const int NIW = 4*1024*DM, NOW = 4*DM*DI;
  k_cvt2<<<dim3((NIW+255)/256,2),256,0,stream>>>(INW[0],INW[1], iwh, iwl, NIW);
  k_cvt2<<<dim3((NOW+255)/256,2),256,0,stream>>>(OW[0], OW[1],  owh, owl, NOW);

  k_tokenize<<<NTOK/TT,256,0,stream>>>(X,EMBP,EMBF,EMBD,WLEN,BLEN,WIAT,BIAT,WFUS,BFUS,GTOK,BTOK,feat,fh,fl);
  for (int layer=0; layer<4; layer++){
    size_t iwoff = (size_t)layer*1024*DM;
    size_t owoff = (size_t)layer*DM*DI;
    // in_proj (MFMA): (4096x1024) = feat(4096x256) @ Wp^T
    k_gemmM<<<dim3(1024/64,4096/64,2),256,0,stream>>>(
      fh,fl,fh,fl,256,
      iwh+iwoff, iwl+iwoff, iwh+NIW+iwoff, iwl+NIW+iwoff, 256,
      xz, xz+XZS, 1024);
    // conv + silu, both dirs
    k_conv2<<<dim3(NTOK*DI/256,2),256,0,stream>>>(xz,
      CW[0]+(size_t)layer*512*4, CW[1]+(size_t)layer*512*4,
      CB[0]+(size_t)layer*512,   CB[1]+(size_t)layer*512, xc);
    // x_proj split-K (fp32): (4096x48) = xc(4096x512) @ Wx^T
    hipMemsetAsync(xdbl, 0, sizeof(float)*2*XDS, stream);
    k_gemmSK<<<dim3(4,64,2),256,0,stream>>>(
      xc, xc+XCS, 512,
      XPW[0]+(size_t)layer*48*512, XPW[1]+(size_t)layer*48*512, 512,
      xdbl, xdbl+XDS, 48);
    // chunked scan (delta fused)
    k_scanA<<<dim3(NC,NB,2),512,0,stream>>>(xc,xdbl,
      AL[0]+(size_t)layer*512*16, AL[1]+(size_t)layer*512*16,
      DTW[0]+(size_t)layer*512*16, DTW[1]+(size_t)layer*512*16,
      DTB[0]+(size_t)layer*512,    DTB[1]+(size_t)layer*512,
      sumA,sumS);
    k_scanP<<<dim3(32,NB,2),256,0,stream>>>(sumA,sumS,ent);
    k_scanB<<<dim3(NC,NB,2),512,0,stream>>>(xc,xdbl,xz,
      AL[0]+(size_t)layer*512*16, AL[1]+(size_t)layer*512*16,
      DTW[0]+(size_t)layer*512*16, DTW[1]+(size_t)layer*512*16,
      DTB[0]+(size_t)layer*512,    DTB[1]+(size_t)layer*512,
      DP[0]+(size_t)layer*512,     DP[1]+(size_t)layer*512,
      ent, yh, yl);
    // out_proj (MFMA): (4096x256) = y(4096x512) @ Wo^T
    k_gemmM<<<dim3(256/64,4096/64,2),256,0,stream>>>(
      yh,yl, yh+XCS,yl+XCS, 512,
      owh+owoff, owl+owoff, owh+NOW+owoff, owl+NOW+owoff, 512,
      outf, outb, 256);
    k_resln<<<NTOK,256,0,stream>>>(outf,outb,feat,GN,BNb,fh,fl);
  }
  k_pool<<<dim3(8,NB),256,0,stream>>>(feat,pool);
  k_head<<<NB,256,0,stream>>>(pool,WH1,BH1,WH2,BH2,(float*)d_out);
}